// Round 6
// baseline (645.135 us; speedup 1.0000x reference)
//
#include <hip/hip_runtime.h>
#include <math.h>

#define NN 10000
#define EE 160000
#define H 128
#define LAYERS 3
#define NRBF 20
#define RADIUS 5.0f
#define PI_F 3.14159265358979323846f

using f16    = _Float16;
using half8  = __attribute__((ext_vector_type(8)))  _Float16;
using f32x16 = __attribute__((ext_vector_type(16))) float;
using u32x4  = __attribute__((ext_vector_type(4)))  unsigned int;

__device__ __forceinline__ float clipf(float x){ return fminf(fmaxf(x, -1e4f), 1e4f); }
__device__ __forceinline__ float siluf(float x){ return x / (1.0f + __expf(-x)); }

// ---------------- CSR build ----------------
__global__ __launch_bounds__(256) void hist_kernel(const int* __restrict__ send, int* __restrict__ cnt){
    int e = blockIdx.x * 256 + threadIdx.x;
    if (e < EE) atomicAdd(&cnt[send[e]], 1);
}

__global__ __launch_bounds__(1024) void scan_kernel(const int* __restrict__ cnt,
                                                    int* __restrict__ row_ptr,
                                                    int* __restrict__ cursor){
    __shared__ int part[1024];
    int t = threadIdx.x;
    int base = t * 10;
    int local[10];
    int sum = 0;
    #pragma unroll
    for (int i = 0; i < 10; i++){
        int idx = base + i;
        local[i] = (idx < NN) ? cnt[idx] : 0;
        sum += local[i];
    }
    part[t] = sum;
    __syncthreads();
    for (int off = 1; off < 1024; off <<= 1){
        int val = (t >= off) ? part[t - off] : 0;
        __syncthreads();
        part[t] += val;
        __syncthreads();
    }
    int run = (t > 0) ? part[t-1] : 0;
    #pragma unroll
    for (int i = 0; i < 10; i++){
        int idx = base + i;
        if (idx < NN){ row_ptr[idx] = run; cursor[idx] = run; run += local[i]; }
    }
    if (t == 1023) row_ptr[NN] = part[1023];
}

// scatter + edge features fused: fp16 P row [dir0,dir1,dir2, phi*cut[0..19], cut] at CSR slot
__global__ __launch_bounds__(256) void build_kernel(const float* __restrict__ ev,
                                                    const int* __restrict__ send,
                                                    const int* __restrict__ recv,
                                                    int* __restrict__ cursor,
                                                    int* __restrict__ recv_s,
                                                    f16* __restrict__ Ps){
    int e = blockIdx.x * 256 + threadIdx.x;
    if (e >= EE) return;
    int p = atomicAdd(&cursor[send[e]], 1);
    recv_s[p] = recv[e];
    float x = ev[e*3+0], y = ev[e*3+1], z = ev[e*3+2];
    float d = sqrtf(x*x + y*y + z*z + 1e-8f);
    float inv = 1.0f / d;
    float cut = (d < RADIUS) ? 0.5f * (__cosf(PI_F * d / RADIUS) + 1.0f) : 0.0f;
    union { u32x4 q[3]; f16 h[24]; } o;
    o.h[0] = (f16)(x*inv); o.h[1] = (f16)(y*inv); o.h[2] = (f16)(z*inv);
    #pragma unroll
    for (int k = 0; k < NRBF; k++){
        float mu = RADIUS * (float)k / (float)(NRBF - 1);
        float t = d - mu;
        o.h[3+k] = (f16)(__expf(-8.0f * t * t) * cut);
    }
    o.h[23] = (f16)cut;
    u32x4* dst = (u32x4*)(Ps + (size_t)p*24);
    dst[0] = o.q[0]; dst[1] = o.q[1]; dst[2] = o.q[2];
}

// ---------------- weight convert: fp32 [K][N] -> fp16 transposed [N][K] ----------------
__global__ __launch_bounds__(256) void wconv_kernel(const float* __restrict__ iW1, const float* __restrict__ iW2,
                                                    const float* __restrict__ vW,  const float* __restrict__ mW1,
                                                    const float* __restrict__ mW2,
                                                    f16* __restrict__ iW1T, f16* __restrict__ iW2T,
                                                    f16* __restrict__ vWT,  f16* __restrict__ mW1T,
                                                    f16* __restrict__ mW2T){
    int idx = blockIdx.x*256 + threadIdx.x;
    if (idx >= 3*180224) return;
    int l = idx / 180224;
    int r = idx % 180224;
    float val; f16* dst;
    if (r < 16384){                 // iW1 [128][128]
        int n = r >> 7, k = r & 127;
        val = iW1[l*16384 + k*128 + n]; dst = iW1T + l*16384 + r;
    } else if (r < 65536){          // iW2 [128][384]
        int r2 = r - 16384; int n = r2 >> 7, k = r2 & 127;
        val = iW2[l*49152 + k*384 + n]; dst = iW2T + l*49152 + r2;
    } else if (r < 98304){          // vW [128][256]
        int r2 = r - 65536; int n = r2 >> 7, k = r2 & 127;
        val = vW[l*32768 + k*256 + n]; dst = vWT + l*32768 + r2;
    } else if (r < 131072){         // mW1 [256][128]
        int r2 = r - 98304; int n = r2 >> 8, k = r2 & 255;
        val = mW1[l*32768 + k*128 + n]; dst = mW1T + l*32768 + r2;
    } else {                        // mW2 [128][384]
        int r2 = r - 131072; int n = r2 >> 7, k = r2 & 127;
        val = mW2[l*49152 + k*384 + n]; dst = mW2T + l*49152 + r2;
    }
    *dst = (f16)val;
}

// ---------------- embedding ----------------
__global__ __launch_bounds__(256) void embed_kernel(const int* __restrict__ z,
                                                    const float* __restrict__ emb,
                                                    float* __restrict__ s, f16* __restrict__ sh){
    int idx = blockIdx.x * 256 + threadIdx.x;
    if (idx >= NN * H) return;
    int n = idx >> 7, h = idx & 127;
    float val = emb[z[n]*H + h];
    s[idx] = val;
    sh[idx] = (f16)val;
}

// ---------------- MFMA GEMM: out[M][NTOT] = epi(A[M][K] @ W), W transposed fp16 WT[NTOT][K] ----------------
template<int K, int NTOT, bool SILU, bool BIAS, int MODE, typename OT>
__global__ __launch_bounds__(256) void mgemm_kernel(const f16* __restrict__ A,
                                                    const f16* __restrict__ A2,
                                                    const f16* __restrict__ WT,
                                                    const float* __restrict__ bias,
                                                    OT* __restrict__ out, int M){
    __shared__ f16 As[64][K+8];
    int t = threadIdx.x;
    int n0 = blockIdx.x * 64;
    {
        int row = t >> 2;
        int seg0 = (t & 3) * (K/4);
        bool valid = (n0 + row) < M;
        #pragma unroll
        for (int j = 0; j < K/32; j++){
            int k = seg0 + j*8;
            half8 val = {};
            if (valid){
                if (MODE == 0) val = *(const half8*)(A + (size_t)(n0+row)*K + k);
                else {
                    const f16* base = (k < 128) ? A : A2;
                    int ko = k & 127;
                    val = *(const half8*)(base + (size_t)(n0+row)*128 + ko);
                }
            }
            *(half8*)&As[row][k] = val;
        }
    }
    __syncthreads();
    int lane = t & 63, w = t >> 6;
    int wr = w >> 1, wc = w & 1;
    int arow = wr*32 + (lane & 31);
    int bcol = blockIdx.y*64 + wc*32 + (lane & 31);
    int koff = (lane >> 5) * 8;
    const f16* ap = &As[arow][koff];
    const f16* bp = WT + (size_t)bcol*K + koff;
    f32x16 acc = {};
    #pragma unroll
    for (int kc = 0; kc < K/16; kc++){
        half8 af = *(const half8*)(ap + kc*16);
        half8 bf = *(const half8*)(bp + kc*16);
        acc = __builtin_amdgcn_mfma_f32_32x32x16_f16(af, bf, acc, 0, 0, 0);
    }
    float bv = BIAS ? bias[bcol] : 0.0f;
    int rbase = n0 + wr*32 + 4*(lane>>5);
    #pragma unroll
    for (int r = 0; r < 16; r++){
        int row = rbase + (r&3) + 8*(r>>2);
        if (row < M){
            float val = acc[r] + bv;
            if (SILU) val = siluf(val);
            out[(size_t)row*NTOT + bcol] = (OT)val;
        }
    }
}

// ---------------- message: one node per block, edges split across the two 128-lane halves ----------------
__global__ __launch_bounds__(256) void msg_kernel(const f16* __restrict__ Ps,
                                                  const int* __restrict__ recv_s,
                                                  const int* __restrict__ row_ptr,
                                                  const f16* __restrict__ xh,
                                                  const f16* __restrict__ vh,
                                                  const float* __restrict__ fW, const float* __restrict__ fb,
                                                  float* __restrict__ s, f16* __restrict__ sh,
                                                  float* __restrict__ v, f16* __restrict__ v2h, int l){
    __shared__ float red[4][128];
    int t = threadIdx.x;
    int h = t & 127;
    int half = t >> 7;
    int n = blockIdx.x;
    int col0 = l*384 + h;
    float wf0[NRBF], wf1[NRBF], wf2[NRBF];
    #pragma unroll
    for (int k = 0; k < NRBF; k++){
        const float* w = fW + k*1152 + col0;
        wf0[k] = w[0]; wf1[k] = w[128]; wf2[k] = w[256];
    }
    float b0 = fb[col0], b1 = fb[col0+128], b2 = fb[col0+256];
    int beg = row_ptr[n], end = row_ptr[n+1];
    int mid = (beg + end + 1) >> 1;
    int lo = half ? mid : beg;
    int hi = half ? end : mid;
    float ds = 0.0f, dv0 = 0.0f, dv1 = 0.0f, dv2 = 0.0f;
    for (int idx = lo; idx < hi; idx++){
        const u32x4* pp = (const u32x4*)(Ps + (size_t)idx*24);
        union { u32x4 q[3]; f16 ph[24]; } u;
        u.q[0] = __builtin_nontemporal_load(pp);
        u.q[1] = __builtin_nontemporal_load(pp+1);
        u.q[2] = __builtin_nontemporal_load(pp+2);
        int r = __builtin_nontemporal_load(&recv_s[idx]);
        float cut = (float)u.ph[23];
        float f0 = b0*cut, f1 = b1*cut, f2 = b2*cut;
        #pragma unroll
        for (int k = 0; k < NRBF; k++){
            float pk = (float)u.ph[3+k];
            f0 = fmaf(pk, wf0[k], f0);
            f1 = fmaf(pk, wf1[k], f1);
            f2 = fmaf(pk, wf2[k], f2);
        }
        const f16* xr = xh + (size_t)r*384;
        float a = f1 * (float)xr[128+h];
        float b = f2 * (float)xr[256+h];
        ds = fmaf(f0, (float)xr[h], ds);
        const f16* vp = vh + (size_t)r*384;
        dv0 = fmaf(a, (float)u.ph[0], fmaf(b, (float)vp[h],     dv0));
        dv1 = fmaf(a, (float)u.ph[1], fmaf(b, (float)vp[128+h], dv1));
        dv2 = fmaf(a, (float)u.ph[2], fmaf(b, (float)vp[256+h], dv2));
    }
    if (half){
        red[0][h] = ds; red[1][h] = dv0; red[2][h] = dv1; red[3][h] = dv2;
    }
    __syncthreads();
    if (!half){
        ds  += red[0][h]; dv0 += red[1][h]; dv1 += red[2][h]; dv2 += red[3][h];
        int si = n*H + h;
        float sv = s[si] + clipf(ds);
        s[si] = sv; sh[si] = (f16)sv;
        size_t vb = (size_t)n*384 + h;
        float nv0 = v[vb]     + clipf(dv0);
        float nv1 = v[vb+128] + clipf(dv1);
        float nv2 = v[vb+256] + clipf(dv2);
        v[vb]     = nv0; v2h[vb]     = (f16)nv0;
        v[vb+128] = nv1; v2h[vb+128] = (f16)nv1;
        v[vb+256] = nv2; v2h[vb+256] = (f16)nv2;
    }
}

// ---------------- vnorm + dot(vl,vr) from fp16 vlr ----------------
__global__ __launch_bounds__(256) void u1_kernel(const f16* __restrict__ vlr,
                                                 f16* __restrict__ vnormh, float* __restrict__ dotl){
    int idx = blockIdx.x * 256 + threadIdx.x;
    if (idx >= NN*H) return;
    int n = idx >> 7, h = idx & 127;
    const f16* b = vlr + (size_t)n*768 + h;
    float l0 = (float)b[0],   l1 = (float)b[256], l2 = (float)b[512];
    float r0 = (float)b[128], r1 = (float)b[384], r2 = (float)b[640];
    vnormh[idx] = (f16)sqrtf(l0*l0 + l1*l1 + l2*l2 + 1e-8f);
    dotl[idx]   = l0*r0 + l1*r1 + l2*r2;
}

// ---------------- final update ----------------
__global__ __launch_bounds__(256) void u4_kernel(const f16* __restrict__ mm, const float* __restrict__ dotl,
                                                 const f16* __restrict__ vlr,
                                                 float* __restrict__ s, f16* __restrict__ sh,
                                                 float* __restrict__ v, f16* __restrict__ vh){
    int idx = blockIdx.x * 256 + threadIdx.x;
    if (idx >= NN*H) return;
    int n = idx >> 7, h = idx & 127;
    const f16* mp = mm + (size_t)n*384;
    float m0 = (float)mp[h], m1 = (float)mp[128+h], m2 = (float)mp[256+h];
    float sv = s[idx] + clipf(m0 + m2*dotl[idx]);
    s[idx] = sv; sh[idx] = (f16)sv;
    const f16* br = vlr + (size_t)n*768 + 128 + h;
    size_t vb = (size_t)n*384 + h;
    float nv0 = v[vb]     + clipf(m1 * (float)br[0]);
    float nv1 = v[vb+128] + clipf(m1 * (float)br[256]);
    float nv2 = v[vb+256] + clipf(m1 * (float)br[512]);
    v[vb]     = nv0; vh[vb]     = (f16)nv0;
    v[vb+128] = nv1; vh[vb+128] = (f16)nv1;
    v[vb+256] = nv2; vh[vb+256] = (f16)nv2;
}

extern "C" void kernel_launch(void* const* d_in, const int* in_sizes, int n_in,
                              void* d_out, int out_size, void* d_ws, size_t ws_size,
                              hipStream_t stream) {
    const int*   z    = (const int*)  d_in[0];
    const float* ev   = (const float*)d_in[1];
    const int*   send = (const int*)  d_in[2];
    const int*   recv = (const int*)  d_in[3];
    const float* emb  = (const float*)d_in[4];
    const float* fW   = (const float*)d_in[5];
    const float* fb   = (const float*)d_in[6];
    const float* iW1  = (const float*)d_in[7];
    const float* ib1  = (const float*)d_in[8];
    const float* iW2  = (const float*)d_in[9];
    const float* ib2  = (const float*)d_in[10];
    const float* mW1  = (const float*)d_in[11];
    const float* mb1  = (const float*)d_in[12];
    const float* mW2  = (const float*)d_in[13];
    const float* mb2  = (const float*)d_in[14];
    const float* vW   = (const float*)d_in[15];

    float* s = (float*)d_out;          // [N,H] fp32 state
    float* v = s + NN*H;               // [N,3,H] fp32 state (in place)

    char* base = (char*)d_ws;
    f16*   Ps     = (f16*)base;   base += (size_t)EE*24*2;      // 7.68 MB CSR-ordered edge feats
    int*   recvs  = (int*)base;   base += (size_t)EE*4;         // 0.64 MB
    f16*   xh     = (f16*)base;                                  // union: xh / mm fp16 [N][384]
    f16*   mmh    = (f16*)base;   base += (size_t)NN*384*2;     // 7.68 MB
    f16*   hidh   = (f16*)base;   base += (size_t)NN*128*2;     // 2.56 MB
    f16*   v2h    = (f16*)base;   base += (size_t)NN*384*2;     // 7.68 MB
    f16*   vh     = (f16*)base;   base += (size_t)NN*384*2;     // 7.68 MB
    f16*   vlr    = (f16*)base;   base += (size_t)NN*768*2;     // 15.36 MB
    f16*   vnormh = (f16*)base;   base += (size_t)NN*128*2;     // 2.56 MB
    float* dotl   = (float*)base; base += (size_t)NN*128*4;     // 5.12 MB
    f16*   sh     = (f16*)base;   base += (size_t)NN*128*2;     // 2.56 MB
    f16*   iW1T   = (f16*)base;   base += (size_t)3*16384*2;
    f16*   iW2T   = (f16*)base;   base += (size_t)3*49152*2;
    f16*   vWT    = (f16*)base;   base += (size_t)3*32768*2;
    f16*   mW1T   = (f16*)base;   base += (size_t)3*32768*2;
    f16*   mW2T   = (f16*)base;   base += (size_t)3*49152*2;
    int* cnt      = (int*)base;   base += (size_t)NN*4;
    int* row_ptr  = (int*)base;   base += (size_t)(NN+1)*4;
    int* cursor   = (int*)base;

    hipMemsetAsync(cnt, 0, NN*sizeof(int), stream);
    hist_kernel<<<(EE+255)/256, 256, 0, stream>>>(send, cnt);
    scan_kernel<<<1, 1024, 0, stream>>>(cnt, row_ptr, cursor);
    build_kernel<<<(EE+255)/256, 256, 0, stream>>>(ev, send, recv, cursor, recvs, Ps);
    wconv_kernel<<<(3*180224+255)/256, 256, 0, stream>>>(iW1, iW2, vW, mW1, mW2,
                                                         iW1T, iW2T, vWT, mW1T, mW2T);
    embed_kernel<<<(NN*H+255)/256, 256, 0, stream>>>(z, emb, s, sh);
    hipMemsetAsync(v, 0, (size_t)NN*384*sizeof(float), stream);
    hipMemsetAsync(vh, 0, (size_t)NN*384*sizeof(f16), stream);

    const int MB  = (NN  + 63) / 64;     // 157
    const int MB3 = (3*NN + 63) / 64;    // 469

    for (int l = 0; l < LAYERS; l++){
        mgemm_kernel<128,128,true, true, 0,f16><<<dim3(MB,2), 256, 0, stream>>>(sh,   nullptr, iW1T + l*16384, ib1 + l*H,   hidh, NN);
        mgemm_kernel<128,384,false,true, 0,f16><<<dim3(MB,6), 256, 0, stream>>>(hidh, nullptr, iW2T + l*49152, ib2 + l*384, xh,   NN);
        msg_kernel<<<NN, 256, 0, stream>>>(Ps, recvs, row_ptr, xh, vh, fW, fb, s, sh, v, v2h, l);
        mgemm_kernel<128,256,false,false,0,f16><<<dim3(MB3,4), 256, 0, stream>>>(v2h, nullptr, vWT + l*32768, nullptr, vlr, 3*NN);
        u1_kernel<<<(NN*H + 255)/256, 256, 0, stream>>>(vlr, vnormh, dotl);
        mgemm_kernel<256,128,true, true, 1,f16><<<dim3(MB,2), 256, 0, stream>>>(sh,   vnormh,  mW1T + l*32768, mb1 + l*H,   hidh, NN);
        mgemm_kernel<128,384,false,true, 0,f16><<<dim3(MB,6), 256, 0, stream>>>(hidh, nullptr, mW2T + l*49152, mb2 + l*384, mmh, NN);
        u4_kernel<<<(NN*H + 255)/256, 256, 0, stream>>>(mmh, dotl, vlr, s, sh, v, vh);
    }
}

// Round 7
// 497.980 us; speedup vs baseline: 1.2955x; 1.2955x over previous
//
#include <hip/hip_runtime.h>
#include <math.h>

#define NN 10000
#define EE 160000
#define H 128
#define LAYERS 3
#define NRBF 20
#define RADIUS 5.0f
#define PI_F 3.14159265358979323846f

using f16    = _Float16;
using h2     = __attribute__((ext_vector_type(2)))  _Float16;
using half8  = __attribute__((ext_vector_type(8)))  _Float16;
using f32x16 = __attribute__((ext_vector_type(16))) float;
using u32x4  = __attribute__((ext_vector_type(4)))  unsigned int;

__device__ __forceinline__ float clipf(float x){ return fminf(fmaxf(x, -1e4f), 1e4f); }
__device__ __forceinline__ float siluf(float x){ return x / (1.0f + __expf(-x)); }

// ---------------- CSR build ----------------
__global__ __launch_bounds__(256) void hist_kernel(const int* __restrict__ send, int* __restrict__ cnt){
    int e = blockIdx.x * 256 + threadIdx.x;
    if (e < EE) atomicAdd(&cnt[send[e]], 1);
}

__global__ __launch_bounds__(1024) void scan_kernel(const int* __restrict__ cnt,
                                                    int* __restrict__ row_ptr,
                                                    int* __restrict__ cursor){
    __shared__ int part[1024];
    int t = threadIdx.x;
    int base = t * 10;
    int local[10];
    int sum = 0;
    #pragma unroll
    for (int i = 0; i < 10; i++){
        int idx = base + i;
        local[i] = (idx < NN) ? cnt[idx] : 0;
        sum += local[i];
    }
    part[t] = sum;
    __syncthreads();
    for (int off = 1; off < 1024; off <<= 1){
        int val = (t >= off) ? part[t - off] : 0;
        __syncthreads();
        part[t] += val;
        __syncthreads();
    }
    int run = (t > 0) ? part[t-1] : 0;
    #pragma unroll
    for (int i = 0; i < 10; i++){
        int idx = base + i;
        if (idx < NN){ row_ptr[idx] = run; cursor[idx] = run; run += local[i]; }
    }
    if (t == 1023) row_ptr[NN] = part[1023];
}

// scatter + edge features fused: fp16 P row [phi*cut[0..19], cut, dir0, dir1, dir2] at CSR slot
__global__ __launch_bounds__(256) void build_kernel(const float* __restrict__ ev,
                                                    const int* __restrict__ send,
                                                    const int* __restrict__ recv,
                                                    int* __restrict__ cursor,
                                                    int* __restrict__ recv_s,
                                                    f16* __restrict__ Ps){
    int e = blockIdx.x * 256 + threadIdx.x;
    if (e >= EE) return;
    int p = atomicAdd(&cursor[send[e]], 1);
    recv_s[p] = recv[e];
    float x = ev[e*3+0], y = ev[e*3+1], z = ev[e*3+2];
    float d = sqrtf(x*x + y*y + z*z + 1e-8f);
    float inv = 1.0f / d;
    float cut = (d < RADIUS) ? 0.5f * (__cosf(PI_F * d / RADIUS) + 1.0f) : 0.0f;
    union { u32x4 q[3]; f16 h[24]; } o;
    #pragma unroll
    for (int k = 0; k < NRBF; k++){
        float mu = RADIUS * (float)k / (float)(NRBF - 1);
        float t = d - mu;
        o.h[k] = (f16)(__expf(-8.0f * t * t) * cut);
    }
    o.h[20] = (f16)cut;
    o.h[21] = (f16)(x*inv); o.h[22] = (f16)(y*inv); o.h[23] = (f16)(z*inv);
    u32x4* dst = (u32x4*)(Ps + (size_t)p*24);
    dst[0] = o.q[0]; dst[1] = o.q[1]; dst[2] = o.q[2];
}

// ---------------- weight convert: fp32 [K][N] -> fp16 transposed [N][K] ----------------
__global__ __launch_bounds__(256) void wconv_kernel(const float* __restrict__ iW1, const float* __restrict__ iW2,
                                                    const float* __restrict__ vW,  const float* __restrict__ mW1,
                                                    const float* __restrict__ mW2,
                                                    f16* __restrict__ iW1T, f16* __restrict__ iW2T,
                                                    f16* __restrict__ vWT,  f16* __restrict__ mW1T,
                                                    f16* __restrict__ mW2T){
    int idx = blockIdx.x*256 + threadIdx.x;
    if (idx >= 3*180224) return;
    int l = idx / 180224;
    int r = idx % 180224;
    float val; f16* dst;
    if (r < 16384){                 // iW1 [128][128]
        int n = r >> 7, k = r & 127;
        val = iW1[l*16384 + k*128 + n]; dst = iW1T + l*16384 + r;
    } else if (r < 65536){          // iW2 [128][384]
        int r2 = r - 16384; int n = r2 >> 7, k = r2 & 127;
        val = iW2[l*49152 + k*384 + n]; dst = iW2T + l*49152 + r2;
    } else if (r < 98304){          // vW [128][256]
        int r2 = r - 65536; int n = r2 >> 7, k = r2 & 127;
        val = vW[l*32768 + k*256 + n]; dst = vWT + l*32768 + r2;
    } else if (r < 131072){         // mW1 [256][128]
        int r2 = r - 98304; int n = r2 >> 8, k = r2 & 255;
        val = mW1[l*32768 + k*128 + n]; dst = mW1T + l*32768 + r2;
    } else {                        // mW2 [128][384]
        int r2 = r - 131072; int n = r2 >> 7, k = r2 & 127;
        val = mW2[l*49152 + k*384 + n]; dst = mW2T + l*49152 + r2;
    }
    *dst = (f16)val;
}

// ---------------- embedding ----------------
__global__ __launch_bounds__(256) void embed_kernel(const int* __restrict__ z,
                                                    const float* __restrict__ emb,
                                                    float* __restrict__ s, f16* __restrict__ sh){
    int idx = blockIdx.x * 256 + threadIdx.x;
    if (idx >= NN * H) return;
    int n = idx >> 7, h = idx & 127;
    float val = emb[z[n]*H + h];
    s[idx] = val;
    sh[idx] = (f16)val;
}

// ---------------- MFMA GEMM: out[M][NTOT] = epi(A[M][K] @ W), W transposed fp16 WT[NTOT][K] ----------------
template<int K, int NTOT, bool SILU, bool BIAS, int MODE, typename OT>
__global__ __launch_bounds__(256) void mgemm_kernel(const f16* __restrict__ A,
                                                    const f16* __restrict__ A2,
                                                    const f16* __restrict__ WT,
                                                    const float* __restrict__ bias,
                                                    OT* __restrict__ out, int M){
    __shared__ f16 As[64][K+8];
    int t = threadIdx.x;
    int n0 = blockIdx.x * 64;
    {
        int row = t >> 2;
        int seg0 = (t & 3) * (K/4);
        bool valid = (n0 + row) < M;
        #pragma unroll
        for (int j = 0; j < K/32; j++){
            int k = seg0 + j*8;
            half8 val = {};
            if (valid){
                if (MODE == 0) val = *(const half8*)(A + (size_t)(n0+row)*K + k);
                else {
                    const f16* base = (k < 128) ? A : A2;
                    int ko = k & 127;
                    val = *(const half8*)(base + (size_t)(n0+row)*128 + ko);
                }
            }
            *(half8*)&As[row][k] = val;
        }
    }
    __syncthreads();
    int lane = t & 63, w = t >> 6;
    int wr = w >> 1, wc = w & 1;
    int arow = wr*32 + (lane & 31);
    int bcol = blockIdx.y*64 + wc*32 + (lane & 31);
    int koff = (lane >> 5) * 8;
    const f16* ap = &As[arow][koff];
    const f16* bp = WT + (size_t)bcol*K + koff;
    f32x16 acc = {};
    #pragma unroll
    for (int kc = 0; kc < K/16; kc++){
        half8 af = *(const half8*)(ap + kc*16);
        half8 bf = *(const half8*)(bp + kc*16);
        acc = __builtin_amdgcn_mfma_f32_32x32x16_f16(af, bf, acc, 0, 0, 0);
    }
    float bv = BIAS ? bias[bcol] : 0.0f;
    int rbase = n0 + wr*32 + 4*(lane>>5);
    #pragma unroll
    for (int r = 0; r < 16; r++){
        int row = rbase + (r&3) + 8*(r>>2);
        if (row < M){
            float val = acc[r] + bv;
            if (SILU) val = siluf(val);
            out[(size_t)row*NTOT + bcol] = (OT)val;
        }
    }
}

// ---------------- message: 2 nodes per block, packed-fp16 filter dot ----------------
__global__ __launch_bounds__(256) void msg_kernel(const f16* __restrict__ Ps,
                                                  const int* __restrict__ recv_s,
                                                  const int* __restrict__ row_ptr,
                                                  const f16* __restrict__ xh,
                                                  const f16* __restrict__ vh,
                                                  const float* __restrict__ fW, const float* __restrict__ fb,
                                                  float* __restrict__ s, f16* __restrict__ sh,
                                                  float* __restrict__ v, f16* __restrict__ v2h, int l){
    int t = threadIdx.x;
    int h = t & 127;
    int n = blockIdx.x * 2 + (t >> 7);
    int col0 = l*384 + h;
    // filter weights as half2 pairs over k: 30 VGPRs total
    h2 wf0[10], wf1[10], wf2[10];
    #pragma unroll
    for (int k = 0; k < 10; k++){
        const float* wa = fW + (2*k)*1152 + col0;
        const float* wb = fW + (2*k+1)*1152 + col0;
        wf0[k] = h2{(f16)wa[0],   (f16)wb[0]};
        wf1[k] = h2{(f16)wa[128], (f16)wb[128]};
        wf2[k] = h2{(f16)wa[256], (f16)wb[256]};
    }
    float b0 = fb[col0], b1 = fb[col0+128], b2 = fb[col0+256];
    int beg = row_ptr[n], end = row_ptr[n+1];
    float ds = 0.0f, dv0 = 0.0f, dv1 = 0.0f, dv2 = 0.0f;
    #pragma unroll 2
    for (int idx = beg; idx < end; idx++){
        const u32x4* pp = (const u32x4*)(Ps + (size_t)idx*24);
        union { u32x4 q[3]; h2 p2[12]; f16 ph[24]; } u;
        u.q[0] = pp[0]; u.q[1] = pp[1]; u.q[2] = pp[2];
        int r = recv_s[idx];
        h2 a0 = {}, a1 = {}, a2v = {};
        #pragma unroll
        for (int k = 0; k < 10; k++){
            h2 pk = u.p2[k];
            a0 += pk * wf0[k];
            a1 += pk * wf1[k];
            a2v += pk * wf2[k];
        }
        float cut = (float)u.ph[20];
        float f0 = fmaf(b0, cut, (float)a0.x + (float)a0.y);
        float f1 = fmaf(b1, cut, (float)a1.x + (float)a1.y);
        float f2 = fmaf(b2, cut, (float)a2v.x + (float)a2v.y);
        const f16* xr = xh + (size_t)r*384;
        float a = f1 * (float)xr[128+h];
        float b = f2 * (float)xr[256+h];
        ds = fmaf(f0, (float)xr[h], ds);
        const f16* vp = vh + (size_t)r*384;
        dv0 = fmaf(a, (float)u.ph[21], fmaf(b, (float)vp[h],     dv0));
        dv1 = fmaf(a, (float)u.ph[22], fmaf(b, (float)vp[128+h], dv1));
        dv2 = fmaf(a, (float)u.ph[23], fmaf(b, (float)vp[256+h], dv2));
    }
    int si = n*H + h;
    float sv = s[si] + clipf(ds);
    s[si] = sv; sh[si] = (f16)sv;
    size_t vb = (size_t)n*384 + h;
    float nv0 = v[vb]     + clipf(dv0);
    float nv1 = v[vb+128] + clipf(dv1);
    float nv2 = v[vb+256] + clipf(dv2);
    v[vb]     = nv0; v2h[vb]     = (f16)nv0;
    v[vb+128] = nv1; v2h[vb+128] = (f16)nv1;
    v[vb+256] = nv2; v2h[vb+256] = (f16)nv2;
}

// ---------------- vnorm + dot(vl,vr) from fp16 vlr ----------------
__global__ __launch_bounds__(256) void u1_kernel(const f16* __restrict__ vlr,
                                                 f16* __restrict__ vnormh, float* __restrict__ dotl){
    int idx = blockIdx.x * 256 + threadIdx.x;
    if (idx >= NN*H) return;
    int n = idx >> 7, h = idx & 127;
    const f16* b = vlr + (size_t)n*768 + h;
    float l0 = (float)b[0],   l1 = (float)b[256], l2 = (float)b[512];
    float r0 = (float)b[128], r1 = (float)b[384], r2 = (float)b[640];
    vnormh[idx] = (f16)sqrtf(l0*l0 + l1*l1 + l2*l2 + 1e-8f);
    dotl[idx]   = l0*r0 + l1*r1 + l2*r2;
}

// ---------------- final update ----------------
__global__ __launch_bounds__(256) void u4_kernel(const f16* __restrict__ mm, const float* __restrict__ dotl,
                                                 const f16* __restrict__ vlr,
                                                 float* __restrict__ s, f16* __restrict__ sh,
                                                 float* __restrict__ v, f16* __restrict__ vh){
    int idx = blockIdx.x * 256 + threadIdx.x;
    if (idx >= NN*H) return;
    int n = idx >> 7, h = idx & 127;
    const f16* mp = mm + (size_t)n*384;
    float m0 = (float)mp[h], m1 = (float)mp[128+h], m2 = (float)mp[256+h];
    float sv = s[idx] + clipf(m0 + m2*dotl[idx]);
    s[idx] = sv; sh[idx] = (f16)sv;
    const f16* br = vlr + (size_t)n*768 + 128 + h;
    size_t vb = (size_t)n*384 + h;
    float nv0 = v[vb]     + clipf(m1 * (float)br[0]);
    float nv1 = v[vb+128] + clipf(m1 * (float)br[256]);
    float nv2 = v[vb+256] + clipf(m1 * (float)br[512]);
    v[vb]     = nv0; vh[vb]     = (f16)nv0;
    v[vb+128] = nv1; vh[vb+128] = (f16)nv1;
    v[vb+256] = nv2; vh[vb+256] = (f16)nv2;
}

extern "C" void kernel_launch(void* const* d_in, const int* in_sizes, int n_in,
                              void* d_out, int out_size, void* d_ws, size_t ws_size,
                              hipStream_t stream) {
    const int*   z    = (const int*)  d_in[0];
    const float* ev   = (const float*)d_in[1];
    const int*   send = (const int*)  d_in[2];
    const int*   recv = (const int*)  d_in[3];
    const float* emb  = (const float*)d_in[4];
    const float* fW   = (const float*)d_in[5];
    const float* fb   = (const float*)d_in[6];
    const float* iW1  = (const float*)d_in[7];
    const float* ib1  = (const float*)d_in[8];
    const float* iW2  = (const float*)d_in[9];
    const float* ib2  = (const float*)d_in[10];
    const float* mW1  = (const float*)d_in[11];
    const float* mb1  = (const float*)d_in[12];
    const float* mW2  = (const float*)d_in[13];
    const float* mb2  = (const float*)d_in[14];
    const float* vW   = (const float*)d_in[15];

    float* s = (float*)d_out;          // [N,H] fp32 state
    float* v = s + NN*H;               // [N,3,H] fp32 state (in place)

    char* base = (char*)d_ws;
    f16*   Ps     = (f16*)base;   base += (size_t)EE*24*2;      // 7.68 MB CSR-ordered edge feats
    int*   recvs  = (int*)base;   base += (size_t)EE*4;         // 0.64 MB
    f16*   xh     = (f16*)base;                                  // union: xh / mm fp16 [N][384]
    f16*   mmh    = (f16*)base;   base += (size_t)NN*384*2;     // 7.68 MB
    f16*   hidh   = (f16*)base;   base += (size_t)NN*128*2;     // 2.56 MB
    f16*   v2h    = (f16*)base;   base += (size_t)NN*384*2;     // 7.68 MB
    f16*   vh     = (f16*)base;   base += (size_t)NN*384*2;     // 7.68 MB
    f16*   vlr    = (f16*)base;   base += (size_t)NN*768*2;     // 15.36 MB
    f16*   vnormh = (f16*)base;   base += (size_t)NN*128*2;     // 2.56 MB
    float* dotl   = (float*)base; base += (size_t)NN*128*4;     // 5.12 MB
    f16*   sh     = (f16*)base;   base += (size_t)NN*128*2;     // 2.56 MB
    f16*   iW1T   = (f16*)base;   base += (size_t)3*16384*2;
    f16*   iW2T   = (f16*)base;   base += (size_t)3*49152*2;
    f16*   vWT    = (f16*)base;   base += (size_t)3*32768*2;
    f16*   mW1T   = (f16*)base;   base += (size_t)3*32768*2;
    f16*   mW2T   = (f16*)base;   base += (size_t)3*49152*2;
    int* cnt      = (int*)base;   base += (size_t)NN*4;
    int* row_ptr  = (int*)base;   base += (size_t)(NN+1)*4;
    int* cursor   = (int*)base;

    hipMemsetAsync(cnt, 0, NN*sizeof(int), stream);
    hist_kernel<<<(EE+255)/256, 256, 0, stream>>>(send, cnt);
    scan_kernel<<<1, 1024, 0, stream>>>(cnt, row_ptr, cursor);
    build_kernel<<<(EE+255)/256, 256, 0, stream>>>(ev, send, recv, cursor, recvs, Ps);
    wconv_kernel<<<(3*180224+255)/256, 256, 0, stream>>>(iW1, iW2, vW, mW1, mW2,
                                                         iW1T, iW2T, vWT, mW1T, mW2T);
    embed_kernel<<<(NN*H+255)/256, 256, 0, stream>>>(z, emb, s, sh);
    hipMemsetAsync(v, 0, (size_t)NN*384*sizeof(float), stream);
    hipMemsetAsync(vh, 0, (size_t)NN*384*sizeof(f16), stream);

    const int MB  = (NN  + 63) / 64;     // 157
    const int MB3 = (3*NN + 63) / 64;    // 469

    for (int l = 0; l < LAYERS; l++){
        mgemm_kernel<128,128,true, true, 0,f16><<<dim3(MB,2), 256, 0, stream>>>(sh,   nullptr, iW1T + l*16384, ib1 + l*H,   hidh, NN);
        mgemm_kernel<128,384,false,true, 0,f16><<<dim3(MB,6), 256, 0, stream>>>(hidh, nullptr, iW2T + l*49152, ib2 + l*384, xh,   NN);
        msg_kernel<<<NN/2, 256, 0, stream>>>(Ps, recvs, row_ptr, xh, vh, fW, fb, s, sh, v, v2h, l);
        mgemm_kernel<128,256,false,false,0,f16><<<dim3(MB3,4), 256, 0, stream>>>(v2h, nullptr, vWT + l*32768, nullptr, vlr, 3*NN);
        u1_kernel<<<(NN*H + 255)/256, 256, 0, stream>>>(vlr, vnormh, dotl);
        mgemm_kernel<256,128,true, true, 1,f16><<<dim3(MB,2), 256, 0, stream>>>(sh,   vnormh,  mW1T + l*32768, mb1 + l*H,   hidh, NN);
        mgemm_kernel<128,384,false,true, 0,f16><<<dim3(MB,6), 256, 0, stream>>>(hidh, nullptr, mW2T + l*49152, mb2 + l*384, mmh, NN);
        u4_kernel<<<(NN*H + 255)/256, 256, 0, stream>>>(mmh, dotl, vlr, s, sh, v, vh);
    }
}

// Round 8
// 448.862 us; speedup vs baseline: 1.4373x; 1.1094x over previous
//
#include <hip/hip_runtime.h>
#include <math.h>

#define NN 10000
#define EE 160000
#define H 128
#define LAYERS 3
#define NRBF 20
#define RADIUS 5.0f
#define PI_F 3.14159265358979323846f

using f16    = _Float16;
using h2     = __attribute__((ext_vector_type(2)))  _Float16;
using half8  = __attribute__((ext_vector_type(8)))  _Float16;
using f32x16 = __attribute__((ext_vector_type(16))) float;
using u32x4  = __attribute__((ext_vector_type(4)))  unsigned int;

__device__ __forceinline__ float clipf(float x){ return fminf(fmaxf(x, -1e4f), 1e4f); }
__device__ __forceinline__ float siluf(float x){ return x / (1.0f + __expf(-x)); }

// ---------------- CSR build ----------------
__global__ __launch_bounds__(256) void hist_kernel(const int* __restrict__ send, int* __restrict__ cnt){
    int e = blockIdx.x * 256 + threadIdx.x;
    if (e < EE) atomicAdd(&cnt[send[e]], 1);
}

__global__ __launch_bounds__(1024) void scan_kernel(const int* __restrict__ cnt,
                                                    int* __restrict__ row_ptr,
                                                    int* __restrict__ cursor){
    __shared__ int part[1024];
    int t = threadIdx.x;
    int base = t * 10;
    int local[10];
    int sum = 0;
    #pragma unroll
    for (int i = 0; i < 10; i++){
        int idx = base + i;
        local[i] = (idx < NN) ? cnt[idx] : 0;
        sum += local[i];
    }
    part[t] = sum;
    __syncthreads();
    for (int off = 1; off < 1024; off <<= 1){
        int val = (t >= off) ? part[t - off] : 0;
        __syncthreads();
        part[t] += val;
        __syncthreads();
    }
    int run = (t > 0) ? part[t-1] : 0;
    #pragma unroll
    for (int i = 0; i < 10; i++){
        int idx = base + i;
        if (idx < NN){ row_ptr[idx] = run; cursor[idx] = run; run += local[i]; }
    }
    if (t == 1023) row_ptr[NN] = part[1023];
}

// scatter + edge features fused: fp16 P row [phi*cut[0..19], cut, dir0, dir1, dir2] at CSR slot
__global__ __launch_bounds__(256) void build_kernel(const float* __restrict__ ev,
                                                    const int* __restrict__ send,
                                                    const int* __restrict__ recv,
                                                    int* __restrict__ cursor,
                                                    int* __restrict__ recv_s,
                                                    f16* __restrict__ Ps){
    int e = blockIdx.x * 256 + threadIdx.x;
    if (e >= EE) return;
    int p = atomicAdd(&cursor[send[e]], 1);
    recv_s[p] = recv[e];
    float x = ev[e*3+0], y = ev[e*3+1], z = ev[e*3+2];
    float d = sqrtf(x*x + y*y + z*z + 1e-8f);
    float inv = 1.0f / d;
    float cut = (d < RADIUS) ? 0.5f * (__cosf(PI_F * d / RADIUS) + 1.0f) : 0.0f;
    union { u32x4 q[3]; f16 h[24]; } o;
    #pragma unroll
    for (int k = 0; k < NRBF; k++){
        float mu = RADIUS * (float)k / (float)(NRBF - 1);
        float t = d - mu;
        o.h[k] = (f16)(__expf(-8.0f * t * t) * cut);
    }
    o.h[20] = (f16)cut;
    o.h[21] = (f16)(x*inv); o.h[22] = (f16)(y*inv); o.h[23] = (f16)(z*inv);
    u32x4* dst = (u32x4*)(Ps + (size_t)p*24);
    dst[0] = o.q[0]; dst[1] = o.q[1]; dst[2] = o.q[2];
}

// ---------------- weight convert: fp32 [K][N] -> fp16 transposed [N][K] ----------------
__global__ __launch_bounds__(256) void wconv_kernel(const float* __restrict__ iW1, const float* __restrict__ iW2,
                                                    const float* __restrict__ vW,  const float* __restrict__ mW1,
                                                    const float* __restrict__ mW2,
                                                    f16* __restrict__ iW1T, f16* __restrict__ iW2T,
                                                    f16* __restrict__ vWT,  f16* __restrict__ mW1T,
                                                    f16* __restrict__ mW2T){
    int idx = blockIdx.x*256 + threadIdx.x;
    if (idx >= 3*180224) return;
    int l = idx / 180224;
    int r = idx % 180224;
    float val; f16* dst;
    if (r < 16384){                 // iW1 [128][128]
        int n = r >> 7, k = r & 127;
        val = iW1[l*16384 + k*128 + n]; dst = iW1T + l*16384 + r;
    } else if (r < 65536){          // iW2 [128][384]
        int r2 = r - 16384; int n = r2 >> 7, k = r2 & 127;
        val = iW2[l*49152 + k*384 + n]; dst = iW2T + l*49152 + r2;
    } else if (r < 98304){          // vW [128][256]
        int r2 = r - 65536; int n = r2 >> 7, k = r2 & 127;
        val = vW[l*32768 + k*256 + n]; dst = vWT + l*32768 + r2;
    } else if (r < 131072){         // mW1 [256][128]
        int r2 = r - 98304; int n = r2 >> 8, k = r2 & 255;
        val = mW1[l*32768 + k*128 + n]; dst = mW1T + l*32768 + r2;
    } else {                        // mW2 [128][384]
        int r2 = r - 131072; int n = r2 >> 7, k = r2 & 127;
        val = mW2[l*49152 + k*384 + n]; dst = mW2T + l*49152 + r2;
    }
    *dst = (f16)val;
}

// ---------------- embedding ----------------
__global__ __launch_bounds__(256) void embed_kernel(const int* __restrict__ z,
                                                    const float* __restrict__ emb,
                                                    float* __restrict__ s, f16* __restrict__ sh){
    int idx = blockIdx.x * 256 + threadIdx.x;
    if (idx >= NN * H) return;
    int n = idx >> 7, h = idx & 127;
    float val = emb[z[n]*H + h];
    s[idx] = val;
    sh[idx] = (f16)val;
}

// ---------------- MFMA GEMM (kept for vW): out = A[M][K]@W, WT[NTOT][K] fp16 ----------------
template<int K, int NTOT, bool SILU, bool BIAS, int MODE, typename OT>
__global__ __launch_bounds__(256) void mgemm_kernel(const f16* __restrict__ A,
                                                    const f16* __restrict__ A2,
                                                    const f16* __restrict__ WT,
                                                    const float* __restrict__ bias,
                                                    OT* __restrict__ out, int M){
    __shared__ f16 As[64][K+8];
    int t = threadIdx.x;
    int n0 = blockIdx.x * 64;
    {
        int row = t >> 2;
        int seg0 = (t & 3) * (K/4);
        bool valid = (n0 + row) < M;
        #pragma unroll
        for (int j = 0; j < K/32; j++){
            int k = seg0 + j*8;
            half8 val = {};
            if (valid){
                if (MODE == 0) val = *(const half8*)(A + (size_t)(n0+row)*K + k);
                else {
                    const f16* base = (k < 128) ? A : A2;
                    int ko = k & 127;
                    val = *(const half8*)(base + (size_t)(n0+row)*128 + ko);
                }
            }
            *(half8*)&As[row][k] = val;
        }
    }
    __syncthreads();
    int lane = t & 63, w = t >> 6;
    int wr = w >> 1, wc = w & 1;
    int arow = wr*32 + (lane & 31);
    int bcol = blockIdx.y*64 + wc*32 + (lane & 31);
    int koff = (lane >> 5) * 8;
    const f16* ap = &As[arow][koff];
    const f16* bp = WT + (size_t)bcol*K + koff;
    f32x16 acc = {};
    #pragma unroll
    for (int kc = 0; kc < K/16; kc++){
        half8 af = *(const half8*)(ap + kc*16);
        half8 bf = *(const half8*)(bp + kc*16);
        acc = __builtin_amdgcn_mfma_f32_32x32x16_f16(af, bf, acc, 0, 0, 0);
    }
    float bv = BIAS ? bias[bcol] : 0.0f;
    int rbase = n0 + wr*32 + 4*(lane>>5);
    #pragma unroll
    for (int r = 0; r < 16; r++){
        int row = rbase + (r&3) + 8*(r>>2);
        if (row < M){
            float val = acc[r] + bv;
            if (SILU) val = siluf(val);
            out[(size_t)row*NTOT + bcol] = (OT)val;
        }
    }
}

// ---------------- fused 2-layer MLP: out[M][384] = silu(A@W1+b1)@W2+b2, hid via LDS ----------------
// 64 nodes/block, 4 waves. W1T [128][K1], W2T [384][128] fp16 transposed.
template<int K1, bool CONCAT>
__global__ __launch_bounds__(256) void mlp_kernel(const f16* __restrict__ A,
                                                  const f16* __restrict__ A2,
                                                  const f16* __restrict__ W1T,
                                                  const float* __restrict__ b1,
                                                  const f16* __restrict__ W2T,
                                                  const float* __restrict__ b2,
                                                  f16* __restrict__ out, int M){
    __shared__ f16 As[64][K1+8];
    __shared__ f16 Hs[64][136];
    int t = threadIdx.x;
    int n0 = blockIdx.x * 64;
    {
        int row = t >> 2;
        int seg0 = (t & 3) * (K1/4);
        bool valid = (n0 + row) < M;
        #pragma unroll
        for (int j = 0; j < K1/32; j++){
            int k = seg0 + j*8;
            half8 val = {};
            if (valid){
                if (!CONCAT) val = *(const half8*)(A + (size_t)(n0+row)*K1 + k);
                else {
                    const f16* base = (k < 128) ? A : A2;
                    val = *(const half8*)(base + (size_t)(n0+row)*128 + (k & 127));
                }
            }
            *(half8*)&As[row][k] = val;
        }
    }
    __syncthreads();
    int lane = t & 63, w = t >> 6;
    int koff = (lane >> 5) * 8;
    int ar = lane & 31;
    // GEMM1: hid[64][128] = silu(A@W1+b1); wave w owns cols w*32..+31, both row groups
    {
        int bcol = w*32 + (lane & 31);
        const f16* bp = W1T + (size_t)bcol*K1 + koff;
        f32x16 acc0 = {}, acc1 = {};
        #pragma unroll
        for (int kc = 0; kc < K1/16; kc++){
            half8 bf = *(const half8*)(bp + kc*16);
            half8 a0 = *(const half8*)(&As[ar][koff + kc*16]);
            half8 a1 = *(const half8*)(&As[32+ar][koff + kc*16]);
            acc0 = __builtin_amdgcn_mfma_f32_32x32x16_f16(a0, bf, acc0, 0, 0, 0);
            acc1 = __builtin_amdgcn_mfma_f32_32x32x16_f16(a1, bf, acc1, 0, 0, 0);
        }
        float bv = b1[bcol];
        #pragma unroll
        for (int r = 0; r < 16; r++){
            int row = (r&3) + 8*(r>>2) + 4*(lane>>5);
            Hs[row][bcol]    = (f16)siluf(acc0[r] + bv);
            Hs[32+row][bcol] = (f16)siluf(acc1[r] + bv);
        }
    }
    __syncthreads();
    // GEMM2: out[64][384] = hid@W2+b2; wave w owns col-tiles {w, w+4, w+8}
    #pragma unroll
    for (int cc = 0; cc < 3; cc++){
        int bcol = (w + cc*4)*32 + (lane & 31);
        const f16* bp = W2T + (size_t)bcol*128 + koff;
        f32x16 acc0 = {}, acc1 = {};
        #pragma unroll
        for (int kc = 0; kc < 8; kc++){
            half8 bf = *(const half8*)(bp + kc*16);
            half8 a0 = *(const half8*)(&Hs[ar][koff + kc*16]);
            half8 a1 = *(const half8*)(&Hs[32+ar][koff + kc*16]);
            acc0 = __builtin_amdgcn_mfma_f32_32x32x16_f16(a0, bf, acc0, 0, 0, 0);
            acc1 = __builtin_amdgcn_mfma_f32_32x32x16_f16(a1, bf, acc1, 0, 0, 0);
        }
        float bv = b2[bcol];
        #pragma unroll
        for (int r = 0; r < 16; r++){
            int row = (r&3) + 8*(r>>2) + 4*(lane>>5);
            int g0 = n0 + row, g1 = n0 + 32 + row;
            if (g0 < M) out[(size_t)g0*384 + bcol] = (f16)(acc0[r] + bv);
            if (g1 < M) out[(size_t)g1*384 + bcol] = (f16)(acc1[r] + bv);
        }
    }
}

// ---------------- message: 4 nodes/block, 64 lanes/node, 2 h per lane ----------------
__global__ __launch_bounds__(256) void msg_kernel(const f16* __restrict__ Ps,
                                                  const int* __restrict__ recv_s,
                                                  const int* __restrict__ row_ptr,
                                                  const f16* __restrict__ xh,
                                                  const f16* __restrict__ vh,
                                                  const float* __restrict__ fW, const float* __restrict__ fb,
                                                  float* __restrict__ s, f16* __restrict__ sh,
                                                  float* __restrict__ v, f16* __restrict__ v2h, int l){
    int t = threadIdx.x;
    int lane = t & 63;
    int n = blockIdx.x * 4 + (t >> 6);
    int h0 = lane * 2;
    int col0 = l*384 + h0;
    // filter weights: h2 over the two h's, 60 VGPRs
    h2 wf0[NRBF], wf1[NRBF], wf2[NRBF];
    #pragma unroll
    for (int k = 0; k < NRBF; k++){
        const float* w = fW + k*1152 + col0;
        wf0[k] = h2{(f16)w[0],   (f16)w[1]};
        wf1[k] = h2{(f16)w[128], (f16)w[129]};
        wf2[k] = h2{(f16)w[256], (f16)w[257]};
    }
    float b0x = fb[col0],     b0y = fb[col0+1];
    float b1x = fb[col0+128], b1y = fb[col0+129];
    float b2x = fb[col0+256], b2y = fb[col0+257];
    int beg = row_ptr[n], end = row_ptr[n+1];
    float ds0=0.f, ds1=0.f, dv00=0.f, dv01=0.f, dv10=0.f, dv11=0.f, dv20=0.f, dv21=0.f;
    #pragma unroll 2
    for (int idx = beg; idx < end; idx++){
        const u32x4* pp = (const u32x4*)(Ps + (size_t)idx*24);
        union { u32x4 q[3]; f16 ph[24]; } u;
        u.q[0] = pp[0]; u.q[1] = pp[1]; u.q[2] = pp[2];
        int r = recv_s[idx];
        h2 f0 = {}, f1 = {}, f2 = {};
        #pragma unroll
        for (int k = 0; k < NRBF; k++){
            f16 pk = u.ph[k];
            h2 pk2 = h2{pk, pk};
            f0 += pk2 * wf0[k];
            f1 += pk2 * wf1[k];
            f2 += pk2 * wf2[k];
        }
        float cut = (float)u.ph[20];
        float F00 = fmaf(b0x, cut, (float)f0.x), F01 = fmaf(b0y, cut, (float)f0.y);
        float F10 = fmaf(b1x, cut, (float)f1.x), F11 = fmaf(b1y, cut, (float)f1.y);
        float F20 = fmaf(b2x, cut, (float)f2.x), F21 = fmaf(b2y, cut, (float)f2.y);
        const f16* xr = xh + (size_t)r*384 + h0;
        h2 X0 = *(const h2*)xr;
        h2 X1 = *(const h2*)(xr + 128);
        h2 X2 = *(const h2*)(xr + 256);
        const f16* vp = vh + (size_t)r*384 + h0;
        h2 V0 = *(const h2*)vp;
        h2 V1 = *(const h2*)(vp + 128);
        h2 V2 = *(const h2*)(vp + 256);
        float d0 = (float)u.ph[21], d1 = (float)u.ph[22], d2 = (float)u.ph[23];
        // h0
        ds0 = fmaf(F00, (float)X0.x, ds0);
        float a0 = F10 * (float)X1.x, bb0 = F20 * (float)X2.x;
        dv00 = fmaf(a0, d0, fmaf(bb0, (float)V0.x, dv00));
        dv10 = fmaf(a0, d1, fmaf(bb0, (float)V1.x, dv10));
        dv20 = fmaf(a0, d2, fmaf(bb0, (float)V2.x, dv20));
        // h0+1
        ds1 = fmaf(F01, (float)X0.y, ds1);
        float a1 = F11 * (float)X1.y, bb1 = F21 * (float)X2.y;
        dv01 = fmaf(a1, d0, fmaf(bb1, (float)V0.y, dv01));
        dv11 = fmaf(a1, d1, fmaf(bb1, (float)V1.y, dv11));
        dv21 = fmaf(a1, d2, fmaf(bb1, (float)V2.y, dv21));
    }
    int si = n*H + h0;
    float sv0 = s[si]   + clipf(ds0);
    float sv1 = s[si+1] + clipf(ds1);
    s[si] = sv0; s[si+1] = sv1;
    *(h2*)&sh[si] = h2{(f16)sv0, (f16)sv1};
    size_t vb = (size_t)n*384 + h0;
    float nv00 = v[vb]     + clipf(dv00), nv01 = v[vb+1]   + clipf(dv01);
    float nv10 = v[vb+128] + clipf(dv10), nv11 = v[vb+129] + clipf(dv11);
    float nv20 = v[vb+256] + clipf(dv20), nv21 = v[vb+257] + clipf(dv21);
    v[vb] = nv00;     v[vb+1] = nv01;
    v[vb+128] = nv10; v[vb+129] = nv11;
    v[vb+256] = nv20; v[vb+257] = nv21;
    *(h2*)&v2h[vb]     = h2{(f16)nv00, (f16)nv01};
    *(h2*)&v2h[vb+128] = h2{(f16)nv10, (f16)nv11};
    *(h2*)&v2h[vb+256] = h2{(f16)nv20, (f16)nv21};
}

// ---------------- vnorm + dot(vl,vr) from fp16 vlr ----------------
__global__ __launch_bounds__(256) void u1_kernel(const f16* __restrict__ vlr,
                                                 f16* __restrict__ vnormh, float* __restrict__ dotl){
    int idx = blockIdx.x * 256 + threadIdx.x;
    if (idx >= NN*H) return;
    int n = idx >> 7, h = idx & 127;
    const f16* b = vlr + (size_t)n*768 + h;
    float l0 = (float)b[0],   l1 = (float)b[256], l2 = (float)b[512];
    float r0 = (float)b[128], r1 = (float)b[384], r2 = (float)b[640];
    vnormh[idx] = (f16)sqrtf(l0*l0 + l1*l1 + l2*l2 + 1e-8f);
    dotl[idx]   = l0*r0 + l1*r1 + l2*r2;
}

// ---------------- final update ----------------
__global__ __launch_bounds__(256) void u4_kernel(const f16* __restrict__ mm, const float* __restrict__ dotl,
                                                 const f16* __restrict__ vlr,
                                                 float* __restrict__ s, f16* __restrict__ sh,
                                                 float* __restrict__ v, f16* __restrict__ vh){
    int idx = blockIdx.x * 256 + threadIdx.x;
    if (idx >= NN*H) return;
    int n = idx >> 7, h = idx & 127;
    const f16* mp = mm + (size_t)n*384;
    float m0 = (float)mp[h], m1 = (float)mp[128+h], m2 = (float)mp[256+h];
    float sv = s[idx] + clipf(m0 + m2*dotl[idx]);
    s[idx] = sv; sh[idx] = (f16)sv;
    const f16* br = vlr + (size_t)n*768 + 128 + h;
    size_t vb = (size_t)n*384 + h;
    float nv0 = v[vb]     + clipf(m1 * (float)br[0]);
    float nv1 = v[vb+128] + clipf(m1 * (float)br[256]);
    float nv2 = v[vb+256] + clipf(m1 * (float)br[512]);
    v[vb]     = nv0; vh[vb]     = (f16)nv0;
    v[vb+128] = nv1; vh[vb+128] = (f16)nv1;
    v[vb+256] = nv2; vh[vb+256] = (f16)nv2;
}

extern "C" void kernel_launch(void* const* d_in, const int* in_sizes, int n_in,
                              void* d_out, int out_size, void* d_ws, size_t ws_size,
                              hipStream_t stream) {
    const int*   z    = (const int*)  d_in[0];
    const float* ev   = (const float*)d_in[1];
    const int*   send = (const int*)  d_in[2];
    const int*   recv = (const int*)  d_in[3];
    const float* emb  = (const float*)d_in[4];
    const float* fW   = (const float*)d_in[5];
    const float* fb   = (const float*)d_in[6];
    const float* iW1  = (const float*)d_in[7];
    const float* ib1  = (const float*)d_in[8];
    const float* iW2  = (const float*)d_in[9];
    const float* ib2  = (const float*)d_in[10];
    const float* mW1  = (const float*)d_in[11];
    const float* mb1  = (const float*)d_in[12];
    const float* mW2  = (const float*)d_in[13];
    const float* mb2  = (const float*)d_in[14];
    const float* vW   = (const float*)d_in[15];

    float* s = (float*)d_out;          // [N,H] fp32 state
    float* v = s + NN*H;               // [N,3,H] fp32 state (in place)

    char* base = (char*)d_ws;
    f16*   Ps     = (f16*)base;   base += (size_t)EE*24*2;      // 7.68 MB CSR-ordered edge feats
    int*   recvs  = (int*)base;   base += (size_t)EE*4;         // 0.64 MB
    f16*   xh     = (f16*)base;                                  // union: xh / mm fp16 [N][384]
    f16*   mmh    = (f16*)base;   base += (size_t)NN*384*2;     // 7.68 MB
    f16*   v2h    = (f16*)base;   base += (size_t)NN*384*2;     // 7.68 MB
    f16*   vh     = (f16*)base;   base += (size_t)NN*384*2;     // 7.68 MB
    f16*   vlr    = (f16*)base;   base += (size_t)NN*768*2;     // 15.36 MB
    f16*   vnormh = (f16*)base;   base += (size_t)NN*128*2;     // 2.56 MB
    float* dotl   = (float*)base; base += (size_t)NN*128*4;     // 5.12 MB
    f16*   sh     = (f16*)base;   base += (size_t)NN*128*2;     // 2.56 MB
    f16*   iW1T   = (f16*)base;   base += (size_t)3*16384*2;
    f16*   iW2T   = (f16*)base;   base += (size_t)3*49152*2;
    f16*   vWT    = (f16*)base;   base += (size_t)3*32768*2;
    f16*   mW1T   = (f16*)base;   base += (size_t)3*32768*2;
    f16*   mW2T   = (f16*)base;   base += (size_t)3*49152*2;
    int* cnt      = (int*)base;   base += (size_t)NN*4;
    int* row_ptr  = (int*)base;   base += (size_t)(NN+1)*4;
    int* cursor   = (int*)base;

    hipMemsetAsync(cnt, 0, NN*sizeof(int), stream);
    hist_kernel<<<(EE+255)/256, 256, 0, stream>>>(send, cnt);
    scan_kernel<<<1, 1024, 0, stream>>>(cnt, row_ptr, cursor);
    build_kernel<<<(EE+255)/256, 256, 0, stream>>>(ev, send, recv, cursor, recvs, Ps);
    wconv_kernel<<<(3*180224+255)/256, 256, 0, stream>>>(iW1, iW2, vW, mW1, mW2,
                                                         iW1T, iW2T, vWT, mW1T, mW2T);
    embed_kernel<<<(NN*H+255)/256, 256, 0, stream>>>(z, emb, s, sh);
    hipMemsetAsync(v, 0, (size_t)NN*384*sizeof(float), stream);
    hipMemsetAsync(vh, 0, (size_t)NN*384*sizeof(f16), stream);

    const int MB  = (NN  + 63) / 64;     // 157
    const int MB3 = (3*NN + 63) / 64;    // 469

    for (int l = 0; l < LAYERS; l++){
        // x = silu(s@iW1+ib1)@iW2+ib2 (fused, -> fp16 xh)
        mlp_kernel<128,false><<<MB, 256, 0, stream>>>(sh, nullptr, iW1T + l*16384, ib1 + l*H,
                                                      iW2T + l*49152, ib2 + l*384, xh, NN);
        // message pass
        msg_kernel<<<NN/4, 256, 0, stream>>>(Ps, recvs, row_ptr, xh, vh, fW, fb, s, sh, v, v2h, l);
        // [vl|vr] = v @ vW -> fp16
        mgemm_kernel<128,256,false,false,0,f16><<<dim3(MB3,4), 256, 0, stream>>>(v2h, nullptr, vWT + l*32768, nullptr, vlr, 3*NN);
        u1_kernel<<<(NN*H + 255)/256, 256, 0, stream>>>(vlr, vnormh, dotl);
        // mm = silu([s|vnorm]@mW1+mb1)@mW2+mb2 (fused, -> fp16 mmh)
        mlp_kernel<256,true><<<MB, 256, 0, stream>>>(sh, vnormh, mW1T + l*32768, mb1 + l*H,
                                                     mW2T + l*49152, mb2 + l*384, mmh, NN);
        u4_kernel<<<(NN*H + 255)/256, 256, 0, stream>>>(mmh, dotl, vlr, s, sh, v, vh);
    }
}

// Round 9
// 412.327 us; speedup vs baseline: 1.5646x; 1.0886x over previous
//
#include <hip/hip_runtime.h>
#include <math.h>

#define NN 10000
#define EE 160000
#define H 128
#define LAYERS 3
#define NRBF 20
#define RADIUS 5.0f
#define PI_F 3.14159265358979323846f

using f16    = _Float16;
using h2     = __attribute__((ext_vector_type(2)))  _Float16;
using half8  = __attribute__((ext_vector_type(8)))  _Float16;
using f32x16 = __attribute__((ext_vector_type(16))) float;
using u32x4  = __attribute__((ext_vector_type(4)))  unsigned int;

__device__ __forceinline__ float clipf(float x){ return fminf(fmaxf(x, -1e4f), 1e4f); }
__device__ __forceinline__ float siluf(float x){ return x / (1.0f + __expf(-x)); }

// ---------------- CSR build ----------------
__global__ __launch_bounds__(256) void hist_kernel(const int* __restrict__ send, int* __restrict__ cnt){
    int e = blockIdx.x * 256 + threadIdx.x;
    if (e < EE) atomicAdd(&cnt[send[e]], 1);
}

__global__ __launch_bounds__(1024) void scan_kernel(const int* __restrict__ cnt,
                                                    int* __restrict__ row_ptr,
                                                    int* __restrict__ cursor){
    __shared__ int part[1024];
    int t = threadIdx.x;
    int base = t * 10;
    int local[10];
    int sum = 0;
    #pragma unroll
    for (int i = 0; i < 10; i++){
        int idx = base + i;
        local[i] = (idx < NN) ? cnt[idx] : 0;
        sum += local[i];
    }
    part[t] = sum;
    __syncthreads();
    for (int off = 1; off < 1024; off <<= 1){
        int val = (t >= off) ? part[t - off] : 0;
        __syncthreads();
        part[t] += val;
        __syncthreads();
    }
    int run = (t > 0) ? part[t-1] : 0;
    #pragma unroll
    for (int i = 0; i < 10; i++){
        int idx = base + i;
        if (idx < NN){ row_ptr[idx] = run; cursor[idx] = run; run += local[i]; }
    }
    if (t == 1023) row_ptr[NN] = part[1023];
}

// scatter + edge features fused: fp16 P row [phi*cut[0..19], cut, dir0, dir1, dir2] at CSR slot
__global__ __launch_bounds__(256) void build_kernel(const float* __restrict__ ev,
                                                    const int* __restrict__ send,
                                                    const int* __restrict__ recv,
                                                    int* __restrict__ cursor,
                                                    int* __restrict__ recv_s,
                                                    f16* __restrict__ Ps){
    int e = blockIdx.x * 256 + threadIdx.x;
    if (e >= EE) return;
    int p = atomicAdd(&cursor[send[e]], 1);
    recv_s[p] = recv[e];
    float x = ev[e*3+0], y = ev[e*3+1], z = ev[e*3+2];
    float d = sqrtf(x*x + y*y + z*z + 1e-8f);
    float inv = 1.0f / d;
    float cut = (d < RADIUS) ? 0.5f * (__cosf(PI_F * d / RADIUS) + 1.0f) : 0.0f;
    union { u32x4 q[3]; f16 h[24]; } o;
    #pragma unroll
    for (int k = 0; k < NRBF; k++){
        float mu = RADIUS * (float)k / (float)(NRBF - 1);
        float t = d - mu;
        o.h[k] = (f16)(__expf(-8.0f * t * t) * cut);
    }
    o.h[20] = (f16)cut;
    o.h[21] = (f16)(x*inv); o.h[22] = (f16)(y*inv); o.h[23] = (f16)(z*inv);
    u32x4* dst = (u32x4*)(Ps + (size_t)p*24);
    dst[0] = o.q[0]; dst[1] = o.q[1]; dst[2] = o.q[2];
}

// ---------------- weight convert: fp32 [K][N] -> fp16 transposed [N][K] ----------------
__global__ __launch_bounds__(256) void wconv_kernel(const float* __restrict__ iW1, const float* __restrict__ iW2,
                                                    const float* __restrict__ vW,  const float* __restrict__ mW1,
                                                    const float* __restrict__ mW2,
                                                    f16* __restrict__ iW1T, f16* __restrict__ iW2T,
                                                    f16* __restrict__ vWT,  f16* __restrict__ mW1T,
                                                    f16* __restrict__ mW2T){
    int idx = blockIdx.x*256 + threadIdx.x;
    if (idx >= 3*180224) return;
    int l = idx / 180224;
    int r = idx % 180224;
    float val; f16* dst;
    if (r < 16384){                 // iW1 [128][128]
        int n = r >> 7, k = r & 127;
        val = iW1[l*16384 + k*128 + n]; dst = iW1T + l*16384 + r;
    } else if (r < 65536){          // iW2 [128][384]
        int r2 = r - 16384; int n = r2 >> 7, k = r2 & 127;
        val = iW2[l*49152 + k*384 + n]; dst = iW2T + l*49152 + r2;
    } else if (r < 98304){          // vW [128][256]
        int r2 = r - 65536; int n = r2 >> 7, k = r2 & 127;
        val = vW[l*32768 + k*256 + n]; dst = vWT + l*32768 + r2;
    } else if (r < 131072){         // mW1 [256][128]
        int r2 = r - 98304; int n = r2 >> 8, k = r2 & 255;
        val = mW1[l*32768 + k*128 + n]; dst = mW1T + l*32768 + r2;
    } else {                        // mW2 [128][384]
        int r2 = r - 131072; int n = r2 >> 7, k = r2 & 127;
        val = mW2[l*49152 + k*384 + n]; dst = mW2T + l*49152 + r2;
    }
    *dst = (f16)val;
}

// ---------------- embedding ----------------
__global__ __launch_bounds__(256) void embed_kernel(const int* __restrict__ z,
                                                    const float* __restrict__ emb,
                                                    float* __restrict__ s, f16* __restrict__ sh){
    int idx = blockIdx.x * 256 + threadIdx.x;
    if (idx >= NN * H) return;
    int n = idx >> 7, h = idx & 127;
    float val = emb[z[n]*H + h];
    s[idx] = val;
    sh[idx] = (f16)val;
}

// ---------------- fused i-MLP: xh[M][384] = silu(A@W1+b1)@W2+b2 ----------------
__global__ __launch_bounds__(256) void mlp1_kernel(const f16* __restrict__ A,
                                                   const f16* __restrict__ W1T,
                                                   const float* __restrict__ b1,
                                                   const f16* __restrict__ W2T,
                                                   const float* __restrict__ b2,
                                                   f16* __restrict__ out){
    __shared__ f16 As[64][136];
    __shared__ f16 Hs[64][136];
    int t = threadIdx.x;
    int n0 = blockIdx.x * 64;
    {
        int row = t >> 2;
        int seg0 = (t & 3) * 32;
        bool valid = (n0 + row) < NN;
        #pragma unroll
        for (int j = 0; j < 4; j++){
            int k = seg0 + j*8;
            half8 val = {};
            if (valid) val = *(const half8*)(A + (size_t)(n0+row)*128 + k);
            *(half8*)&As[row][k] = val;
        }
    }
    __syncthreads();
    int lane = t & 63, w = t >> 6;
    int koff = (lane >> 5) * 8;
    int ar = lane & 31;
    {
        int bcol = w*32 + ar;
        const f16* bp = W1T + (size_t)bcol*128 + koff;
        f32x16 acc0 = {}, acc1 = {};
        #pragma unroll
        for (int kc = 0; kc < 8; kc++){
            half8 bf = *(const half8*)(bp + kc*16);
            half8 a0 = *(const half8*)(&As[ar][koff + kc*16]);
            half8 a1 = *(const half8*)(&As[32+ar][koff + kc*16]);
            acc0 = __builtin_amdgcn_mfma_f32_32x32x16_f16(a0, bf, acc0, 0, 0, 0);
            acc1 = __builtin_amdgcn_mfma_f32_32x32x16_f16(a1, bf, acc1, 0, 0, 0);
        }
        float bv = b1[bcol];
        #pragma unroll
        for (int r = 0; r < 16; r++){
            int row = (r&3) + 8*(r>>2) + 4*(lane>>5);
            Hs[row][bcol]    = (f16)siluf(acc0[r] + bv);
            Hs[32+row][bcol] = (f16)siluf(acc1[r] + bv);
        }
    }
    __syncthreads();
    #pragma unroll
    for (int cc = 0; cc < 3; cc++){
        int bcol = (w + cc*4)*32 + ar;
        const f16* bp = W2T + (size_t)bcol*128 + koff;
        f32x16 acc0 = {}, acc1 = {};
        #pragma unroll
        for (int kc = 0; kc < 8; kc++){
            half8 bf = *(const half8*)(bp + kc*16);
            half8 a0 = *(const half8*)(&Hs[ar][koff + kc*16]);
            half8 a1 = *(const half8*)(&Hs[32+ar][koff + kc*16]);
            acc0 = __builtin_amdgcn_mfma_f32_32x32x16_f16(a0, bf, acc0, 0, 0, 0);
            acc1 = __builtin_amdgcn_mfma_f32_32x32x16_f16(a1, bf, acc1, 0, 0, 0);
        }
        float bv = b2[bcol];
        #pragma unroll
        for (int r = 0; r < 16; r++){
            int row = (r&3) + 8*(r>>2) + 4*(lane>>5);
            int g0 = n0 + row, g1 = n0 + 32 + row;
            if (g0 < NN) out[(size_t)g0*384 + bcol] = (f16)(acc0[r] + bv);
            if (g1 < NN) out[(size_t)g1*384 + bcol] = (f16)(acc1[r] + bv);
        }
    }
}

// ---------------- message: 2 nodes/block (1 wave each), 2 h per lane ----------------
// vh, v2h plane-major [3][N][128]
__global__ __launch_bounds__(128) void msg_kernel(const f16* __restrict__ Ps,
                                                  const int* __restrict__ recv_s,
                                                  const int* __restrict__ row_ptr,
                                                  const f16* __restrict__ xh,
                                                  const f16* __restrict__ vh,
                                                  const float* __restrict__ fW, const float* __restrict__ fb,
                                                  float* __restrict__ s, f16* __restrict__ sh,
                                                  float* __restrict__ v, f16* __restrict__ v2h, int l){
    int t = threadIdx.x;
    int lane = t & 63;
    int n = blockIdx.x * 2 + (t >> 6);
    int h0 = lane * 2;
    int col0 = l*384 + h0;
    h2 wf0[NRBF], wf1[NRBF], wf2[NRBF];
    #pragma unroll
    for (int k = 0; k < NRBF; k++){
        const float* w = fW + k*1152 + col0;
        wf0[k] = h2{(f16)w[0],   (f16)w[1]};
        wf1[k] = h2{(f16)w[128], (f16)w[129]};
        wf2[k] = h2{(f16)w[256], (f16)w[257]};
    }
    float b0x = fb[col0],     b0y = fb[col0+1];
    float b1x = fb[col0+128], b1y = fb[col0+129];
    float b2x = fb[col0+256], b2y = fb[col0+257];
    int beg = row_ptr[n], end = row_ptr[n+1];
    float ds0=0.f, ds1=0.f, dv00=0.f, dv01=0.f, dv10=0.f, dv11=0.f, dv20=0.f, dv21=0.f;
    #pragma unroll 2
    for (int idx = beg; idx < end; idx++){
        const u32x4* pp = (const u32x4*)(Ps + (size_t)idx*24);
        union { u32x4 q[3]; f16 ph[24]; } u;
        u.q[0] = pp[0]; u.q[1] = pp[1]; u.q[2] = pp[2];
        int r = recv_s[idx];
        h2 f0 = {}, f1 = {}, f2 = {};
        #pragma unroll
        for (int k = 0; k < NRBF; k++){
            f16 pk = u.ph[k];
            h2 pk2 = h2{pk, pk};
            f0 += pk2 * wf0[k];
            f1 += pk2 * wf1[k];
            f2 += pk2 * wf2[k];
        }
        float cut = (float)u.ph[20];
        float F00 = fmaf(b0x, cut, (float)f0.x), F01 = fmaf(b0y, cut, (float)f0.y);
        float F10 = fmaf(b1x, cut, (float)f1.x), F11 = fmaf(b1y, cut, (float)f1.y);
        float F20 = fmaf(b2x, cut, (float)f2.x), F21 = fmaf(b2y, cut, (float)f2.y);
        const f16* xr = xh + (size_t)r*384 + h0;
        h2 X0 = *(const h2*)xr;
        h2 X1 = *(const h2*)(xr + 128);
        h2 X2 = *(const h2*)(xr + 256);
        const f16* vp = vh + (size_t)r*128 + h0;
        h2 V0 = *(const h2*)vp;
        h2 V1 = *(const h2*)(vp + (size_t)NN*128);
        h2 V2 = *(const h2*)(vp + (size_t)2*NN*128);
        float d0 = (float)u.ph[21], d1 = (float)u.ph[22], d2 = (float)u.ph[23];
        ds0 = fmaf(F00, (float)X0.x, ds0);
        float a0 = F10 * (float)X1.x, bb0 = F20 * (float)X2.x;
        dv00 = fmaf(a0, d0, fmaf(bb0, (float)V0.x, dv00));
        dv10 = fmaf(a0, d1, fmaf(bb0, (float)V1.x, dv10));
        dv20 = fmaf(a0, d2, fmaf(bb0, (float)V2.x, dv20));
        ds1 = fmaf(F01, (float)X0.y, ds1);
        float a1 = F11 * (float)X1.y, bb1 = F21 * (float)X2.y;
        dv01 = fmaf(a1, d0, fmaf(bb1, (float)V0.y, dv01));
        dv11 = fmaf(a1, d1, fmaf(bb1, (float)V1.y, dv11));
        dv21 = fmaf(a1, d2, fmaf(bb1, (float)V2.y, dv21));
    }
    int si = n*H + h0;
    float sv0 = s[si]   + clipf(ds0);
    float sv1 = s[si+1] + clipf(ds1);
    s[si] = sv0; s[si+1] = sv1;
    *(h2*)&sh[si] = h2{(f16)sv0, (f16)sv1};
    size_t vb = (size_t)n*384 + h0;
    float nv00 = v[vb]     + clipf(dv00), nv01 = v[vb+1]   + clipf(dv01);
    float nv10 = v[vb+128] + clipf(dv10), nv11 = v[vb+129] + clipf(dv11);
    float nv20 = v[vb+256] + clipf(dv20), nv21 = v[vb+257] + clipf(dv21);
    v[vb] = nv00;     v[vb+1] = nv01;
    v[vb+128] = nv10; v[vb+129] = nv11;
    v[vb+256] = nv20; v[vb+257] = nv21;
    size_t pb = (size_t)n*128 + h0;
    *(h2*)&v2h[pb]                    = h2{(f16)nv00, (f16)nv01};
    *(h2*)&v2h[pb + (size_t)NN*128]   = h2{(f16)nv10, (f16)nv11};
    *(h2*)&v2h[pb + (size_t)2*NN*128] = h2{(f16)nv20, (f16)nv21};
}

// ---------------- fused vlr: [vl|vr] = v2 @ vW; vnorm/dot in-register; vl never hits global ----------------
// 32 nodes/block, 4 waves; wave w owns vl-coltile w and vr-coltile w (cols 128+w*32..)
__global__ __launch_bounds__(256) void vlr_kernel(const f16* __restrict__ v2h,   // [3][N][128]
                                                  const f16* __restrict__ vWT,   // [256][128]
                                                  f16* __restrict__ vrh,         // [3][N][128]
                                                  f16* __restrict__ vnormh,      // [N][128]
                                                  float* __restrict__ dotl){     // [N][128]
    __shared__ f16 As[3][32][136];
    int t = threadIdx.x;
    int n0 = blockIdx.x * 32;
    for (int i = t; i < 1536; i += 256){     // 3*32*16 half8-chunks
        int c = i / 512; int rem = i - c*512; int row = rem >> 4; int k8 = (rem & 15) * 8;
        bool valid = (n0 + row) < NN;
        half8 val = {};
        if (valid) val = *(const half8*)(v2h + ((size_t)c*NN + n0 + row)*128 + k8);
        *(half8*)&As[c][row][k8] = val;
    }
    __syncthreads();
    int lane = t & 63, w = t >> 6;
    int ar = lane & 31;
    int koff = (lane >> 5) * 8;
    int jl = w*32 + ar;                      // vl col index [0,128)
    half8 Bl[8], Br[8];
    #pragma unroll
    for (int kc = 0; kc < 8; kc++){
        Bl[kc] = *(const half8*)(vWT + (size_t)jl*128 + koff + kc*16);
        Br[kc] = *(const half8*)(vWT + (size_t)(128+jl)*128 + koff + kc*16);
    }
    f32x16 al[3], arr[3];
    #pragma unroll
    for (int c = 0; c < 3; c++){
        f32x16 accl = {}, accr = {};
        #pragma unroll
        for (int kc = 0; kc < 8; kc++){
            half8 a = *(const half8*)(&As[c][ar][koff + kc*16]);
            accl = __builtin_amdgcn_mfma_f32_32x32x16_f16(a, Bl[kc], accl, 0, 0, 0);
            accr = __builtin_amdgcn_mfma_f32_32x32x16_f16(a, Br[kc], accr, 0, 0, 0);
        }
        al[c] = accl; arr[c] = accr;
    }
    #pragma unroll
    for (int r = 0; r < 16; r++){
        int node = n0 + (r&3) + 8*(r>>2) + 4*(lane>>5);
        if (node < NN){
            float l0=al[0][r], l1=al[1][r], l2=al[2][r];
            float r0=arr[0][r], r1=arr[1][r], r2=arr[2][r];
            size_t si = (size_t)node*128 + jl;
            vnormh[si] = (f16)sqrtf(l0*l0 + l1*l1 + l2*l2 + 1e-8f);
            dotl[si]   = l0*r0 + l1*r1 + l2*r2;
            vrh[si]                    = (f16)r0;
            vrh[si + (size_t)NN*128]   = (f16)r1;
            vrh[si + (size_t)2*NN*128] = (f16)r2;
        }
    }
}

// ---------------- fused m-MLP + u4: mm in-register, final s/v updates ----------------
__global__ __launch_bounds__(256) void mlp2u4_kernel(const f16* __restrict__ shin,
                                                     const f16* __restrict__ vnormh,
                                                     const f16* __restrict__ W1T,   // [128][256]
                                                     const float* __restrict__ b1,
                                                     const f16* __restrict__ W2T,   // [384][128]
                                                     const float* __restrict__ b2,
                                                     const float* __restrict__ dotl,
                                                     const f16* __restrict__ vrh,   // [3][N][128]
                                                     float* __restrict__ s, f16* __restrict__ sh,
                                                     float* __restrict__ v, f16* __restrict__ vh){
    __shared__ f16 As[64][264];
    __shared__ f16 Hs[64][136];
    int t = threadIdx.x;
    int n0 = blockIdx.x * 64;
    {
        int row = t >> 2;
        int seg0 = (t & 3) * 64;
        bool valid = (n0 + row) < NN;
        #pragma unroll
        for (int j = 0; j < 8; j++){
            int k = seg0 + j*8;
            half8 val = {};
            if (valid){
                const f16* base = (k < 128) ? shin : vnormh;
                val = *(const half8*)(base + (size_t)(n0+row)*128 + (k & 127));
            }
            *(half8*)&As[row][k] = val;
        }
    }
    __syncthreads();
    int lane = t & 63, w = t >> 6;
    int koff = (lane >> 5) * 8;
    int ar = lane & 31;
    {
        int bcol = w*32 + ar;
        const f16* bp = W1T + (size_t)bcol*256 + koff;
        f32x16 acc0 = {}, acc1 = {};
        #pragma unroll
        for (int kc = 0; kc < 16; kc++){
            half8 bf = *(const half8*)(bp + kc*16);
            half8 a0 = *(const half8*)(&As[ar][koff + kc*16]);
            half8 a1 = *(const half8*)(&As[32+ar][koff + kc*16]);
            acc0 = __builtin_amdgcn_mfma_f32_32x32x16_f16(a0, bf, acc0, 0, 0, 0);
            acc1 = __builtin_amdgcn_mfma_f32_32x32x16_f16(a1, bf, acc1, 0, 0, 0);
        }
        float bv = b1[bcol];
        #pragma unroll
        for (int r = 0; r < 16; r++){
            int row = (r&3) + 8*(r>>2) + 4*(lane>>5);
            Hs[row][bcol]    = (f16)siluf(acc0[r] + bv);
            Hs[32+row][bcol] = (f16)siluf(acc1[r] + bv);
        }
    }
    __syncthreads();
    // GEMM2: keep all 3 col-group accumulators (mm cols j, 128+j, 256+j in same lane)
    f32x16 acc[3][2];
    #pragma unroll
    for (int cc = 0; cc < 3; cc++){
        int bcol = (w + cc*4)*32 + ar;
        const f16* bp = W2T + (size_t)bcol*128 + koff;
        f32x16 a0 = {}, a1 = {};
        #pragma unroll
        for (int kc = 0; kc < 8; kc++){
            half8 bf = *(const half8*)(bp + kc*16);
            half8 h0v = *(const half8*)(&Hs[ar][koff + kc*16]);
            half8 h1v = *(const half8*)(&Hs[32+ar][koff + kc*16]);
            a0 = __builtin_amdgcn_mfma_f32_32x32x16_f16(h0v, bf, a0, 0, 0, 0);
            a1 = __builtin_amdgcn_mfma_f32_32x32x16_f16(h1v, bf, a1, 0, 0, 0);
        }
        acc[cc][0] = a0; acc[cc][1] = a1;
    }
    int jj = w*32 + ar;
    float bv0 = b2[jj], bv1 = b2[128 + jj], bv2 = b2[256 + jj];
    #pragma unroll
    for (int rg = 0; rg < 2; rg++){
        #pragma unroll
        for (int r = 0; r < 16; r++){
            int node = n0 + rg*32 + (r&3) + 8*(r>>2) + 4*(lane>>5);
            if (node < NN){
                float m0 = acc[0][rg][r] + bv0;
                float m1 = acc[1][rg][r] + bv1;
                float m2 = acc[2][rg][r] + bv2;
                size_t si = (size_t)node*128 + jj;
                float sv = s[si] + clipf(m0 + m2*dotl[si]);
                s[si] = sv; sh[si] = (f16)sv;
                #pragma unroll
                for (int c = 0; c < 3; c++){
                    size_t pi = si + (size_t)c*NN*128;
                    float vrv = (float)vrh[pi];
                    size_t vi = (size_t)node*384 + c*128 + jj;
                    float nv = v[vi] + clipf(m1 * vrv);
                    v[vi] = nv; vh[pi] = (f16)nv;
                }
            }
        }
    }
}

extern "C" void kernel_launch(void* const* d_in, const int* in_sizes, int n_in,
                              void* d_out, int out_size, void* d_ws, size_t ws_size,
                              hipStream_t stream) {
    const int*   z    = (const int*)  d_in[0];
    const float* ev   = (const float*)d_in[1];
    const int*   send = (const int*)  d_in[2];
    const int*   recv = (const int*)  d_in[3];
    const float* emb  = (const float*)d_in[4];
    const float* fW   = (const float*)d_in[5];
    const float* fb   = (const float*)d_in[6];
    const float* iW1  = (const float*)d_in[7];
    const float* ib1  = (const float*)d_in[8];
    const float* iW2  = (const float*)d_in[9];
    const float* ib2  = (const float*)d_in[10];
    const float* mW1  = (const float*)d_in[11];
    const float* mb1  = (const float*)d_in[12];
    const float* mW2  = (const float*)d_in[13];
    const float* mb2  = (const float*)d_in[14];
    const float* vW   = (const float*)d_in[15];

    float* s = (float*)d_out;          // [N,H] fp32 state
    float* v = s + NN*H;               // [N,3,H] fp32 state (in place)

    char* base = (char*)d_ws;
    f16*   Ps     = (f16*)base;   base += (size_t)EE*24*2;      // 7.68 MB
    int*   recvs  = (int*)base;   base += (size_t)EE*4;         // 0.64 MB
    f16*   xh     = (f16*)base;   base += (size_t)NN*384*2;     // 7.68 MB
    f16*   v2h    = (f16*)base;   base += (size_t)3*NN*128*2;   // 7.68 MB plane-major
    f16*   vh     = (f16*)base;   base += (size_t)3*NN*128*2;   // 7.68 MB plane-major
    f16*   vrh    = (f16*)base;   base += (size_t)3*NN*128*2;   // 7.68 MB plane-major
    f16*   vnormh = (f16*)base;   base += (size_t)NN*128*2;     // 2.56 MB
    float* dotl   = (float*)base; base += (size_t)NN*128*4;     // 5.12 MB
    f16*   sh     = (f16*)base;   base += (size_t)NN*128*2;     // 2.56 MB
    f16*   iW1T   = (f16*)base;   base += (size_t)3*16384*2;
    f16*   iW2T   = (f16*)base;   base += (size_t)3*49152*2;
    f16*   vWT    = (f16*)base;   base += (size_t)3*32768*2;
    f16*   mW1T   = (f16*)base;   base += (size_t)3*32768*2;
    f16*   mW2T   = (f16*)base;   base += (size_t)3*49152*2;
    int* cnt      = (int*)base;   base += (size_t)NN*4;
    int* row_ptr  = (int*)base;   base += (size_t)(NN+1)*4;
    int* cursor   = (int*)base;

    hipMemsetAsync(cnt, 0, NN*sizeof(int), stream);
    hist_kernel<<<(EE+255)/256, 256, 0, stream>>>(send, cnt);
    scan_kernel<<<1, 1024, 0, stream>>>(cnt, row_ptr, cursor);
    build_kernel<<<(EE+255)/256, 256, 0, stream>>>(ev, send, recv, cursor, recvs, Ps);
    wconv_kernel<<<(3*180224+255)/256, 256, 0, stream>>>(iW1, iW2, vW, mW1, mW2,
                                                         iW1T, iW2T, vWT, mW1T, mW2T);
    embed_kernel<<<(NN*H+255)/256, 256, 0, stream>>>(z, emb, s, sh);
    hipMemsetAsync(v,  0, (size_t)NN*384*sizeof(float), stream);
    hipMemsetAsync(vh, 0, (size_t)3*NN*128*sizeof(f16), stream);

    const int MB  = (NN + 63) / 64;      // 157
    const int VB  = (NN + 31) / 32;      // 313

    for (int l = 0; l < LAYERS; l++){
        mlp1_kernel<<<MB, 256, 0, stream>>>(sh, iW1T + l*16384, ib1 + l*H,
                                            iW2T + l*49152, ib2 + l*384, xh);
        msg_kernel<<<NN/2, 128, 0, stream>>>(Ps, recvs, row_ptr, xh, vh, fW, fb, s, sh, v, v2h, l);
        vlr_kernel<<<VB, 256, 0, stream>>>(v2h, vWT + l*32768, vrh, vnormh, dotl);
        mlp2u4_kernel<<<MB, 256, 0, stream>>>(sh, vnormh, mW1T + l*32768, mb1 + l*H,
                                              mW2T + l*49152, mb2 + l*384,
                                              dotl, vrh, s, sh, v, vh);
    }
}

// Round 10
// 372.625 us; speedup vs baseline: 1.7313x; 1.1065x over previous
//
#include <hip/hip_runtime.h>
#include <math.h>

#define NN 10000
#define EE 160000
#define H 128
#define LAYERS 3
#define NRBF 20
#define RADIUS 5.0f
#define PI_F 3.14159265358979323846f

using f16    = _Float16;
using h2     = __attribute__((ext_vector_type(2)))  _Float16;
using half8  = __attribute__((ext_vector_type(8)))  _Float16;
using f32x16 = __attribute__((ext_vector_type(16))) float;
using u32x4  = __attribute__((ext_vector_type(4)))  unsigned int;

__device__ __forceinline__ float clipf(float x){ return fminf(fmaxf(x, -1e4f), 1e4f); }
__device__ __forceinline__ float siluf(float x){ return x / (1.0f + __expf(-x)); }

// ---------------- CSR build ----------------
__global__ __launch_bounds__(256) void hist_kernel(const int* __restrict__ send, int* __restrict__ cnt){
    int e = blockIdx.x * 256 + threadIdx.x;
    if (e < EE) atomicAdd(&cnt[send[e]], 1);
}

__global__ __launch_bounds__(1024) void scan_kernel(const int* __restrict__ cnt,
                                                    int* __restrict__ row_ptr,
                                                    int* __restrict__ cursor){
    __shared__ int part[1024];
    int t = threadIdx.x;
    int base = t * 10;
    int local[10];
    int sum = 0;
    #pragma unroll
    for (int i = 0; i < 10; i++){
        int idx = base + i;
        local[i] = (idx < NN) ? cnt[idx] : 0;
        sum += local[i];
    }
    part[t] = sum;
    __syncthreads();
    for (int off = 1; off < 1024; off <<= 1){
        int val = (t >= off) ? part[t - off] : 0;
        __syncthreads();
        part[t] += val;
        __syncthreads();
    }
    int run = (t > 0) ? part[t-1] : 0;
    #pragma unroll
    for (int i = 0; i < 10; i++){
        int idx = base + i;
        if (idx < NN){ row_ptr[idx] = run; cursor[idx] = run; run += local[i]; }
    }
    if (t == 1023) row_ptr[NN] = part[1023];
}

// scatter + edge features fused: fp16 P row [phi*cut[0..19], cut, dir0, dir1, dir2] at CSR slot
__global__ __launch_bounds__(256) void build_kernel(const float* __restrict__ ev,
                                                    const int* __restrict__ send,
                                                    const int* __restrict__ recv,
                                                    int* __restrict__ cursor,
                                                    int* __restrict__ recv_s,
                                                    f16* __restrict__ Ps){
    int e = blockIdx.x * 256 + threadIdx.x;
    if (e >= EE) return;
    int p = atomicAdd(&cursor[send[e]], 1);
    recv_s[p] = recv[e];
    float x = ev[e*3+0], y = ev[e*3+1], z = ev[e*3+2];
    float d = sqrtf(x*x + y*y + z*z + 1e-8f);
    float inv = 1.0f / d;
    float cut = (d < RADIUS) ? 0.5f * (__cosf(PI_F * d / RADIUS) + 1.0f) : 0.0f;
    union { u32x4 q[3]; f16 h[24]; } o;
    #pragma unroll
    for (int k = 0; k < NRBF; k++){
        float mu = RADIUS * (float)k / (float)(NRBF - 1);
        float t = d - mu;
        o.h[k] = (f16)(__expf(-8.0f * t * t) * cut);
    }
    o.h[20] = (f16)cut;
    o.h[21] = (f16)(x*inv); o.h[22] = (f16)(y*inv); o.h[23] = (f16)(z*inv);
    u32x4* dst = (u32x4*)(Ps + (size_t)p*24);
    dst[0] = o.q[0]; dst[1] = o.q[1]; dst[2] = o.q[2];
}

// ---------------- weight convert: fp32 [K][N] -> fp16 transposed [N][K] ----------------
__global__ __launch_bounds__(256) void wconv_kernel(const float* __restrict__ iW1, const float* __restrict__ iW2,
                                                    const float* __restrict__ vW,  const float* __restrict__ mW1,
                                                    const float* __restrict__ mW2,
                                                    f16* __restrict__ iW1T, f16* __restrict__ iW2T,
                                                    f16* __restrict__ vWT,  f16* __restrict__ mW1T,
                                                    f16* __restrict__ mW2T){
    int idx = blockIdx.x*256 + threadIdx.x;
    if (idx >= 3*180224) return;
    int l = idx / 180224;
    int r = idx % 180224;
    float val; f16* dst;
    if (r < 16384){                 // iW1 [128][128]
        int n = r >> 7, k = r & 127;
        val = iW1[l*16384 + k*128 + n]; dst = iW1T + l*16384 + r;
    } else if (r < 65536){          // iW2 [128][384]
        int r2 = r - 16384; int n = r2 >> 7, k = r2 & 127;
        val = iW2[l*49152 + k*384 + n]; dst = iW2T + l*49152 + r2;
    } else if (r < 98304){          // vW [128][256]
        int r2 = r - 65536; int n = r2 >> 7, k = r2 & 127;
        val = vW[l*32768 + k*256 + n]; dst = vWT + l*32768 + r2;
    } else if (r < 131072){         // mW1 [256][128]
        int r2 = r - 98304; int n = r2 >> 8, k = r2 & 255;
        val = mW1[l*32768 + k*128 + n]; dst = mW1T + l*32768 + r2;
    } else {                        // mW2 [128][384]
        int r2 = r - 131072; int n = r2 >> 7, k = r2 & 127;
        val = mW2[l*49152 + k*384 + n]; dst = mW2T + l*49152 + r2;
    }
    *dst = (f16)val;
}

// ---------------- embedding ----------------
__global__ __launch_bounds__(256) void embed_kernel(const int* __restrict__ z,
                                                    const float* __restrict__ emb,
                                                    float* __restrict__ s, f16* __restrict__ sh){
    int idx = blockIdx.x * 256 + threadIdx.x;
    if (idx >= NN * H) return;
    int n = idx >> 7, h = idx & 127;
    float val = emb[z[n]*H + h];
    s[idx] = val;
    sh[idx] = (f16)val;
}

// ---------------- i-MLP: xh[M][384] = silu(A@W1+b1)@W2+b2 ; 32 nodes/block ----------------
__global__ __launch_bounds__(256) void mlp1_kernel(const f16* __restrict__ A,
                                                   const f16* __restrict__ W1T,
                                                   const float* __restrict__ b1,
                                                   const f16* __restrict__ W2T,
                                                   const float* __restrict__ b2,
                                                   f16* __restrict__ out){
    __shared__ f16 As[32][136];
    __shared__ f16 Hs[32][136];
    int t = threadIdx.x;
    int n0 = blockIdx.x * 32;
    for (int i = t; i < 512; i += 256){
        int row = i >> 4, k8 = (i & 15) * 8;
        half8 val = {};
        if (n0 + row < NN) val = *(const half8*)(A + (size_t)(n0+row)*128 + k8);
        *(half8*)&As[row][k8] = val;
    }
    __syncthreads();
    int lane = t & 63, w = t >> 6;
    int ar = lane & 31;
    int koff = (lane >> 5) * 8;
    {
        int bcol = w*32 + ar;
        const f16* bp = W1T + (size_t)bcol*128 + koff;
        f32x16 acc = {};
        #pragma unroll
        for (int kc = 0; kc < 8; kc++){
            half8 bf = *(const half8*)(bp + kc*16);
            half8 a  = *(const half8*)(&As[ar][koff + kc*16]);
            acc = __builtin_amdgcn_mfma_f32_32x32x16_f16(a, bf, acc, 0, 0, 0);
        }
        float bv = b1[bcol];
        #pragma unroll
        for (int r = 0; r < 16; r++){
            int row = (r&3) + 8*(r>>2) + 4*(lane>>5);
            Hs[row][bcol] = (f16)siluf(acc[r] + bv);
        }
    }
    __syncthreads();
    #pragma unroll
    for (int cc = 0; cc < 3; cc++){
        int bcol = (w + cc*4)*32 + ar;
        const f16* bp = W2T + (size_t)bcol*128 + koff;
        f32x16 acc = {};
        #pragma unroll
        for (int kc = 0; kc < 8; kc++){
            half8 bf = *(const half8*)(bp + kc*16);
            half8 a  = *(const half8*)(&Hs[ar][koff + kc*16]);
            acc = __builtin_amdgcn_mfma_f32_32x32x16_f16(a, bf, acc, 0, 0, 0);
        }
        float bv = b2[bcol];
        #pragma unroll
        for (int r = 0; r < 16; r++){
            int row = (r&3) + 8*(r>>2) + 4*(lane>>5);
            int g = n0 + row;
            if (g < NN) out[(size_t)g*384 + bcol] = (f16)(acc[r] + bv);
        }
    }
}

// ---------------- message: 2 nodes/block (1 wave each), 2 h per lane ----------------
// vh, v2h plane-major [3][N][128]
__global__ __launch_bounds__(128) void msg_kernel(const f16* __restrict__ Ps,
                                                  const int* __restrict__ recv_s,
                                                  const int* __restrict__ row_ptr,
                                                  const f16* __restrict__ xh,
                                                  const f16* __restrict__ vh,
                                                  const float* __restrict__ fW, const float* __restrict__ fb,
                                                  float* __restrict__ s, f16* __restrict__ sh,
                                                  float* __restrict__ v, f16* __restrict__ v2h, int l){
    int t = threadIdx.x;
    int lane = t & 63;
    int n = blockIdx.x * 2 + (t >> 6);
    int h0 = lane * 2;
    int col0 = l*384 + h0;
    h2 wf0[NRBF], wf1[NRBF], wf2[NRBF];
    #pragma unroll
    for (int k = 0; k < NRBF; k++){
        const float* w = fW + k*1152 + col0;
        wf0[k] = h2{(f16)w[0],   (f16)w[1]};
        wf1[k] = h2{(f16)w[128], (f16)w[129]};
        wf2[k] = h2{(f16)w[256], (f16)w[257]};
    }
    float b0x = fb[col0],     b0y = fb[col0+1];
    float b1x = fb[col0+128], b1y = fb[col0+129];
    float b2x = fb[col0+256], b2y = fb[col0+257];
    int beg = row_ptr[n], end = row_ptr[n+1];
    float ds0=0.f, ds1=0.f, dv00=0.f, dv01=0.f, dv10=0.f, dv11=0.f, dv20=0.f, dv21=0.f;
    #pragma unroll 2
    for (int idx = beg; idx < end; idx++){
        const u32x4* pp = (const u32x4*)(Ps + (size_t)idx*24);
        union { u32x4 q[3]; f16 ph[24]; } u;
        u.q[0] = pp[0]; u.q[1] = pp[1]; u.q[2] = pp[2];
        int r = recv_s[idx];
        h2 f0 = {}, f1 = {}, f2 = {};
        #pragma unroll
        for (int k = 0; k < NRBF; k++){
            f16 pk = u.ph[k];
            h2 pk2 = h2{pk, pk};
            f0 += pk2 * wf0[k];
            f1 += pk2 * wf1[k];
            f2 += pk2 * wf2[k];
        }
        float cut = (float)u.ph[20];
        float F00 = fmaf(b0x, cut, (float)f0.x), F01 = fmaf(b0y, cut, (float)f0.y);
        float F10 = fmaf(b1x, cut, (float)f1.x), F11 = fmaf(b1y, cut, (float)f1.y);
        float F20 = fmaf(b2x, cut, (float)f2.x), F21 = fmaf(b2y, cut, (float)f2.y);
        const f16* xr = xh + (size_t)r*384 + h0;
        h2 X0 = *(const h2*)xr;
        h2 X1 = *(const h2*)(xr + 128);
        h2 X2 = *(const h2*)(xr + 256);
        const f16* vp = vh + (size_t)r*128 + h0;
        h2 V0 = *(const h2*)vp;
        h2 V1 = *(const h2*)(vp + (size_t)NN*128);
        h2 V2 = *(const h2*)(vp + (size_t)2*NN*128);
        float d0 = (float)u.ph[21], d1 = (float)u.ph[22], d2 = (float)u.ph[23];
        ds0 = fmaf(F00, (float)X0.x, ds0);
        float a0 = F10 * (float)X1.x, bb0 = F20 * (float)X2.x;
        dv00 = fmaf(a0, d0, fmaf(bb0, (float)V0.x, dv00));
        dv10 = fmaf(a0, d1, fmaf(bb0, (float)V1.x, dv10));
        dv20 = fmaf(a0, d2, fmaf(bb0, (float)V2.x, dv20));
        ds1 = fmaf(F01, (float)X0.y, ds1);
        float a1 = F11 * (float)X1.y, bb1 = F21 * (float)X2.y;
        dv01 = fmaf(a1, d0, fmaf(bb1, (float)V0.y, dv01));
        dv11 = fmaf(a1, d1, fmaf(bb1, (float)V1.y, dv11));
        dv21 = fmaf(a1, d2, fmaf(bb1, (float)V2.y, dv21));
    }
    int si = n*H + h0;
    float sv0 = s[si]   + clipf(ds0);
    float sv1 = s[si+1] + clipf(ds1);
    s[si] = sv0; s[si+1] = sv1;
    *(h2*)&sh[si] = h2{(f16)sv0, (f16)sv1};
    size_t vb = (size_t)n*384 + h0;
    float nv00 = v[vb]     + clipf(dv00), nv01 = v[vb+1]   + clipf(dv01);
    float nv10 = v[vb+128] + clipf(dv10), nv11 = v[vb+129] + clipf(dv11);
    float nv20 = v[vb+256] + clipf(dv20), nv21 = v[vb+257] + clipf(dv21);
    v[vb] = nv00;     v[vb+1] = nv01;
    v[vb+128] = nv10; v[vb+129] = nv11;
    v[vb+256] = nv20; v[vb+257] = nv21;
    size_t pb = (size_t)n*128 + h0;
    *(h2*)&v2h[pb]                    = h2{(f16)nv00, (f16)nv01};
    *(h2*)&v2h[pb + (size_t)NN*128]   = h2{(f16)nv10, (f16)nv11};
    *(h2*)&v2h[pb + (size_t)2*NN*128] = h2{(f16)nv20, (f16)nv21};
}

// ---------------- fused vmix: [vl|vr]=v2@vW -> vnorm/dot/vr in-register -> m-MLP -> u4 ----------------
// 32 nodes/block, 4 waves. dot/vr fragment layout == GEMM2 output layout (node=row, col=w*32+(lane&31)).
__global__ __launch_bounds__(256) void vmix_kernel(const f16* __restrict__ v2h,   // [3][N][128]
                                                   const f16* __restrict__ sh_in, // [N][128]
                                                   const f16* __restrict__ vWT,   // [256][128]
                                                   const f16* __restrict__ W1T,   // [128][256]
                                                   const float* __restrict__ b1,
                                                   const f16* __restrict__ W2T,   // [384][128]
                                                   const float* __restrict__ b2,
                                                   float* __restrict__ s, f16* __restrict__ sh,
                                                   float* __restrict__ v, f16* __restrict__ vh){
    __shared__ f16 As3[3][32][136];
    __shared__ f16 ts[32][264];
    __shared__ f16 Hs[32][136];
    int t = threadIdx.x;
    int n0 = blockIdx.x * 32;
    for (int i = t; i < 1536; i += 256){
        int c = i / 512; int rem = i - c*512; int row = rem >> 4; int k8 = (rem & 15) * 8;
        half8 val = {};
        if (n0 + row < NN) val = *(const half8*)(v2h + ((size_t)c*NN + n0 + row)*128 + k8);
        *(half8*)&As3[c][row][k8] = val;
    }
    for (int i = t; i < 512; i += 256){
        int row = i >> 4, k8 = (i & 15) * 8;
        half8 val = {};
        if (n0 + row < NN) val = *(const half8*)(sh_in + (size_t)(n0+row)*128 + k8);
        *(half8*)&ts[row][k8] = val;
    }
    __syncthreads();
    int lane = t & 63, w = t >> 6;
    int ar = lane & 31;
    int koff = (lane >> 5) * 8;
    int jl = w*32 + ar;
    // phase A: vl/vr for 3 planes
    f32x16 al[3], arr[3];
    #pragma unroll
    for (int c = 0; c < 3; c++){
        f32x16 accl = {}, accr = {};
        #pragma unroll
        for (int kc = 0; kc < 8; kc++){
            half8 bl = *(const half8*)(vWT + (size_t)jl*128 + koff + kc*16);
            half8 br = *(const half8*)(vWT + (size_t)(128+jl)*128 + koff + kc*16);
            half8 a  = *(const half8*)(&As3[c][ar][koff + kc*16]);
            accl = __builtin_amdgcn_mfma_f32_32x32x16_f16(a, bl, accl, 0, 0, 0);
            accr = __builtin_amdgcn_mfma_f32_32x32x16_f16(a, br, accr, 0, 0, 0);
        }
        al[c] = accl; arr[c] = accr;
    }
    float dot[16], vr0[16], vr1[16], vr2[16];
    #pragma unroll
    for (int r = 0; r < 16; r++){
        int row = (r&3) + 8*(r>>2) + 4*(lane>>5);
        float l0=al[0][r], l1=al[1][r], l2=al[2][r];
        float r0=arr[0][r], r1=arr[1][r], r2=arr[2][r];
        ts[row][128 + jl] = (f16)sqrtf(l0*l0 + l1*l1 + l2*l2 + 1e-8f);
        dot[r] = l0*r0 + l1*r1 + l2*r2;
        vr0[r] = r0; vr1[r] = r1; vr2[r] = r2;
    }
    __syncthreads();
    // phase B: GEMM1 K=256 -> Hs (silu)
    {
        int bcol = w*32 + ar;
        const f16* bp = W1T + (size_t)bcol*256 + koff;
        f32x16 acc = {};
        #pragma unroll
        for (int kc = 0; kc < 16; kc++){
            half8 bf = *(const half8*)(bp + kc*16);
            half8 a  = *(const half8*)(&ts[ar][koff + kc*16]);
            acc = __builtin_amdgcn_mfma_f32_32x32x16_f16(a, bf, acc, 0, 0, 0);
        }
        float bv = b1[bcol];
        #pragma unroll
        for (int r = 0; r < 16; r++){
            int row = (r&3) + 8*(r>>2) + 4*(lane>>5);
            Hs[row][bcol] = (f16)siluf(acc[r] + bv);
        }
    }
    __syncthreads();
    // phase C: GEMM2 (3 col groups) + u4 epilogue
    f32x16 macc[3];
    #pragma unroll
    for (int cc = 0; cc < 3; cc++){
        int bcol = (w + cc*4)*32 + ar;
        const f16* bp = W2T + (size_t)bcol*128 + koff;
        f32x16 acc = {};
        #pragma unroll
        for (int kc = 0; kc < 8; kc++){
            half8 bf = *(const half8*)(bp + kc*16);
            half8 a  = *(const half8*)(&Hs[ar][koff + kc*16]);
            acc = __builtin_amdgcn_mfma_f32_32x32x16_f16(a, bf, acc, 0, 0, 0);
        }
        macc[cc] = acc;
    }
    int jj = w*32 + ar;
    float bv0 = b2[jj], bv1 = b2[128 + jj], bv2 = b2[256 + jj];
    #pragma unroll
    for (int r = 0; r < 16; r++){
        int node = n0 + (r&3) + 8*(r>>2) + 4*(lane>>5);
        if (node < NN){
            float m0 = macc[0][r] + bv0;
            float m1 = macc[1][r] + bv1;
            float m2 = macc[2][r] + bv2;
            size_t si = (size_t)node*128 + jj;
            float sv = s[si] + clipf(m0 + m2*dot[r]);
            s[si] = sv; sh[si] = (f16)sv;
            size_t vi = (size_t)node*384 + jj;
            float nv0 = v[vi]       + clipf(m1 * vr0[r]);
            float nv1 = v[vi + 128] + clipf(m1 * vr1[r]);
            float nv2 = v[vi + 256] + clipf(m1 * vr2[r]);
            v[vi]       = nv0;
            v[vi + 128] = nv1;
            v[vi + 256] = nv2;
            vh[si]                    = (f16)nv0;
            vh[si + (size_t)NN*128]   = (f16)nv1;
            vh[si + (size_t)2*NN*128] = (f16)nv2;
        }
    }
}

extern "C" void kernel_launch(void* const* d_in, const int* in_sizes, int n_in,
                              void* d_out, int out_size, void* d_ws, size_t ws_size,
                              hipStream_t stream) {
    const int*   z    = (const int*)  d_in[0];
    const float* ev   = (const float*)d_in[1];
    const int*   send = (const int*)  d_in[2];
    const int*   recv = (const int*)  d_in[3];
    const float* emb  = (const float*)d_in[4];
    const float* fW   = (const float*)d_in[5];
    const float* fb   = (const float*)d_in[6];
    const float* iW1  = (const float*)d_in[7];
    const float* ib1  = (const float*)d_in[8];
    const float* iW2  = (const float*)d_in[9];
    const float* ib2  = (const float*)d_in[10];
    const float* mW1  = (const float*)d_in[11];
    const float* mb1  = (const float*)d_in[12];
    const float* mW2  = (const float*)d_in[13];
    const float* mb2  = (const float*)d_in[14];
    const float* vW   = (const float*)d_in[15];

    float* s = (float*)d_out;          // [N,H] fp32 state
    float* v = s + NN*H;               // [N,3,H] fp32 state (in place)

    char* base = (char*)d_ws;
    f16*   Ps     = (f16*)base;   base += (size_t)EE*24*2;      // 7.68 MB
    int*   recvs  = (int*)base;   base += (size_t)EE*4;         // 0.64 MB
    f16*   xh     = (f16*)base;   base += (size_t)NN*384*2;     // 7.68 MB
    f16*   v2h    = (f16*)base;   base += (size_t)3*NN*128*2;   // 7.68 MB plane-major
    f16*   vh     = (f16*)base;   base += (size_t)3*NN*128*2;   // 7.68 MB plane-major
    f16*   sh     = (f16*)base;   base += (size_t)NN*128*2;     // 2.56 MB
    f16*   iW1T   = (f16*)base;   base += (size_t)3*16384*2;
    f16*   iW2T   = (f16*)base;   base += (size_t)3*49152*2;
    f16*   vWT    = (f16*)base;   base += (size_t)3*32768*2;
    f16*   mW1T   = (f16*)base;   base += (size_t)3*32768*2;
    f16*   mW2T   = (f16*)base;   base += (size_t)3*49152*2;
    int* cnt      = (int*)base;   base += (size_t)NN*4;
    int* row_ptr  = (int*)base;   base += (size_t)(NN+1)*4;
    int* cursor   = (int*)base;

    hipMemsetAsync(cnt, 0, NN*sizeof(int), stream);
    hist_kernel<<<(EE+255)/256, 256, 0, stream>>>(send, cnt);
    scan_kernel<<<1, 1024, 0, stream>>>(cnt, row_ptr, cursor);
    build_kernel<<<(EE+255)/256, 256, 0, stream>>>(ev, send, recv, cursor, recvs, Ps);
    wconv_kernel<<<(3*180224+255)/256, 256, 0, stream>>>(iW1, iW2, vW, mW1, mW2,
                                                         iW1T, iW2T, vWT, mW1T, mW2T);
    embed_kernel<<<(NN*H+255)/256, 256, 0, stream>>>(z, emb, s, sh);
    hipMemsetAsync(v,  0, (size_t)NN*384*sizeof(float), stream);
    hipMemsetAsync(vh, 0, (size_t)3*NN*128*sizeof(f16), stream);

    const int MB32 = (NN + 31) / 32;     // 313

    for (int l = 0; l < LAYERS; l++){
        mlp1_kernel<<<MB32, 256, 0, stream>>>(sh, iW1T + l*16384, ib1 + l*H,
                                              iW2T + l*49152, ib2 + l*384, xh);
        msg_kernel<<<NN/2, 128, 0, stream>>>(Ps, recvs, row_ptr, xh, vh, fW, fb, s, sh, v, v2h, l);
        vmix_kernel<<<MB32, 256, 0, stream>>>(v2h, sh, vWT + l*32768,
                                              mW1T + l*32768, mb1 + l*H,
                                              mW2T + l*49152, mb2 + l*384,
                                              s, sh, v, vh);
    }
}